// Round 1
// baseline (1598.342 us; speedup 1.0000x reference)
//
#include <hip/hip_runtime.h>

typedef __attribute__((ext_vector_type(4))) float f32x4;
typedef __attribute__((ext_vector_type(8))) short short8;

#define DEV static __device__ __forceinline__

DEV ushort f2b(float f) {
  union { float f; unsigned u; } v; v.f = f;
  unsigned r = v.u + 0x7FFF + ((v.u >> 16) & 1);
  return (ushort)(r >> 16);
}

// ---------------------------------------------------------------- constants
#define BB    2
#define LL    2048
#define DD    512
#define HH    8
#define EE    64
#define DIN   1024
#define NS    64
#define RR    32
#define BL    4096            // B*L
#define MFMA(a,b,c) __builtin_amdgcn_mfma_f32_16x16x32_bf16((a),(b),(c),0,0,0)

// ---------------------------------------------------------------- f32 -> bf16 multi-convert
struct CvtJobs {
  const float* src[9];
  ushort*      dst[9];
  int          n[9];
};

__global__ __launch_bounds__(256) void cvt_multi(CvtJobs j) {
  int job = blockIdx.y;
  const float* s = j.src[job];
  ushort* d = j.dst[job];
  int n = j.n[job];
  for (int i = blockIdx.x * 256 + threadIdx.x; i < n; i += gridDim.x * 256)
    d[i] = f2b(s[i]);
}

// ---------------------------------------------------------------- generic GEMM: C = A @ W^T (+bias)(+softplus)
// A: [M][K] bf16, W: [N][K] bf16, outF/outB: [M][N]
__global__ __launch_bounds__(256) void gemm_bt(
    const ushort* __restrict__ A, const ushort* __restrict__ W,
    const float* __restrict__ bias, float* __restrict__ outF,
    ushort* __restrict__ outB, int M, int N, int K, int act)
{
  __shared__ ushort As[64][40];
  __shared__ ushort Ws[64][40];
  int m0 = blockIdx.y * 64, n0 = blockIdx.x * 64;
  int tid = threadIdx.x, l = tid & 63, w = tid >> 6;
  int wm = (w >> 1) * 32, wn = (w & 1) * 32;
  int lr = l & 15, kl = (l >> 4) * 8;
  int srow = tid >> 2, sk = (tid & 3) * 8;
  f32x4 acc[2][2] = {};

  for (int k0 = 0; k0 < K; k0 += 32) {
    uint4 av = *(const uint4*)&A[(size_t)(m0 + srow) * K + k0 + sk];
    uint4 wv;
    if (n0 + srow < N) wv = *(const uint4*)&W[(size_t)(n0 + srow) * K + k0 + sk];
    else { wv.x = 0; wv.y = 0; wv.z = 0; wv.w = 0; }
    *(uint4*)&As[srow][sk] = av;
    *(uint4*)&Ws[srow][sk] = wv;
    __syncthreads();
    short8 a0 = *(const short8*)&As[wm + lr][kl];
    short8 a1 = *(const short8*)&As[wm + 16 + lr][kl];
    short8 b0 = *(const short8*)&Ws[wn + lr][kl];
    short8 b1 = *(const short8*)&Ws[wn + 16 + lr][kl];
    acc[0][0] = MFMA(a0, b0, acc[0][0]);
    acc[0][1] = MFMA(a0, b1, acc[0][1]);
    acc[1][0] = MFMA(a1, b0, acc[1][0]);
    acc[1][1] = MFMA(a1, b1, acc[1][1]);
    __syncthreads();
  }

  #pragma unroll
  for (int mi = 0; mi < 2; mi++)
    #pragma unroll
    for (int ni = 0; ni < 2; ni++) {
      int rbase = m0 + wm + mi * 16 + ((l >> 4) << 2);
      int col = n0 + wn + ni * 16 + lr;
      if (col < N) {
        float bval = bias ? bias[col] : 0.f;
        #pragma unroll
        for (int r = 0; r < 4; r++) {
          float v = acc[mi][ni][r] + bval;
          if (act == 1) v = (v > 20.f) ? v : log1pf(__expf(v));
          size_t o = (size_t)(rbase + r) * N + col;
          if (outF) outF[o] = v;
          if (outB) outB[o] = f2b(v);
        }
      }
    }
}

// ---------------------------------------------------------------- flash attention (causal, e=64)
__global__ __launch_bounds__(256) void flash_attn(
    const ushort* __restrict__ qb, const ushort* __restrict__ kb,
    const ushort* __restrict__ vb, ushort* __restrict__ ctx)
{
  __shared__ ushort Qs[64][72];
  __shared__ ushort Ks[64][72];
  __shared__ ushort Vt[64][72];
  __shared__ ushort Ps[64][72];

  int qt = blockIdx.x, h = blockIdx.y, b = blockIdx.z;
  int tid = threadIdx.x, l = tid & 63, w = tid >> 6;
  int w16 = w * 16, lr = l & 15, kl = (l >> 4) * 8;

  // stage Q tile
  for (int i = tid; i < 512; i += 256) {
    int row = i >> 3, c8 = (i & 7) * 8;
    *(uint4*)&Qs[row][c8] =
        *(const uint4*)&qb[((size_t)(b * LL + qt * 64 + row)) * DD + h * EE + c8];
  }
  __syncthreads();

  float m_r[4] = {-1e30f, -1e30f, -1e30f, -1e30f};
  float l_r[4] = {0.f, 0.f, 0.f, 0.f};
  f32x4 oacc[4] = {};

  for (int kv = 0; kv <= qt; kv++) {
    // stage K tile + transposed V tile
    for (int i = tid; i < 512; i += 256) {
      int s = i >> 3, c8 = (i & 7) * 8;
      *(uint4*)&Ks[s][c8] =
          *(const uint4*)&kb[((size_t)(b * LL + kv * 64 + s)) * DD + h * EE + c8];
      uint4 vv = *(const uint4*)&vb[((size_t)(b * LL + kv * 64 + s)) * DD + h * EE + c8];
      const ushort* pv = (const ushort*)&vv;
      #pragma unroll
      for (int jj = 0; jj < 8; jj++) Vt[c8 + jj][s] = pv[jj];
    }
    __syncthreads();

    // S = Q K^T (strip of 16 rows per wave)
    f32x4 sacc[4] = {};
    #pragma unroll
    for (int kk = 0; kk < 2; kk++) {
      short8 aq = *(const short8*)&Qs[w16 + lr][kk * 32 + kl];
      #pragma unroll
      for (int nt = 0; nt < 4; nt++) {
        short8 bk8 = *(const short8*)&Ks[nt * 16 + lr][kk * 32 + kl];
        sacc[nt] = MFMA(aq, bk8, sacc[nt]);
      }
    }

    bool diag = (kv == qt);
    float scl[4];
    #pragma unroll
    for (int r = 0; r < 4; r++) {
      int rloc = w16 + ((l >> 4) << 2) + r;
      float sv[4];
      #pragma unroll
      for (int nt = 0; nt < 4; nt++) {
        float v = sacc[nt][r] * 0.125f;
        if (diag && (nt * 16 + lr) > rloc) v = -1e30f;
        sv[nt] = v;
      }
      float mx = fmaxf(fmaxf(sv[0], sv[1]), fmaxf(sv[2], sv[3]));
      #pragma unroll
      for (int o = 1; o < 16; o <<= 1) mx = fmaxf(mx, __shfl_xor(mx, o));
      float mnew = fmaxf(m_r[r], mx);
      float sc = __expf(m_r[r] - mnew);
      float rs = 0.f;
      #pragma unroll
      for (int nt = 0; nt < 4; nt++) {
        float p = __expf(sv[nt] - mnew);
        rs += p;
        Ps[rloc][nt * 16 + lr] = f2b(p);
      }
      #pragma unroll
      for (int o = 1; o < 16; o <<= 1) rs += __shfl_xor(rs, o);
      l_r[r] = l_r[r] * sc + rs;
      m_r[r] = mnew;
      scl[r] = sc;
    }
    #pragma unroll
    for (int nt = 0; nt < 4; nt++)
      #pragma unroll
      for (int r = 0; r < 4; r++) oacc[nt][r] *= scl[r];

    // O += P @ V  (Vt is [e][s])
    #pragma unroll
    for (int kk = 0; kk < 2; kk++) {
      short8 ap = *(const short8*)&Ps[w16 + lr][kk * 32 + kl];
      #pragma unroll
      for (int nt = 0; nt < 4; nt++) {
        short8 bv8 = *(const short8*)&Vt[nt * 16 + lr][kk * 32 + kl];
        oacc[nt] = MFMA(ap, bv8, oacc[nt]);
      }
    }
    __syncthreads();
  }

  #pragma unroll
  for (int nt = 0; nt < 4; nt++)
    #pragma unroll
    for (int r = 0; r < 4; r++) {
      int row = qt * 64 + w16 + ((l >> 4) << 2) + r;
      float v = oacc[nt][r] / l_r[r];
      ctx[((size_t)(b * LL + row)) * DD + h * EE + nt * 16 + lr] = f2b(v);
    }
}

// ---------------------------------------------------------------- depthwise causal conv (K=4) + SiLU
__global__ __launch_bounds__(256) void conv_silu(
    const float* __restrict__ xz, const float* __restrict__ cw,
    const float* __restrict__ cb, float* __restrict__ u, ushort* __restrict__ ub)
{
  int i = blockIdx.x * 256 + threadIdx.x;
  if (i >= BL * DIN) return;
  int d = i & (DIN - 1);
  int bl = i >> 10;
  int t = bl & (LL - 1);
  int b = bl >> 11;
  float s = cb[d];
  #pragma unroll
  for (int j = 0; j < 4; j++) {
    int tt = t - 3 + j;
    if (tt >= 0) s += xz[((size_t)(b * LL + tt)) * (2 * DIN) + d] * cw[d * 4 + j];
  }
  float r = s / (1.f + __expf(-s));
  u[i] = r;
  ub[i] = f2b(r);
}

// ---------------------------------------------------------------- slice dbc[:, :32] -> bf16
__global__ __launch_bounds__(256) void slice_dt(
    const float* __restrict__ dbc, ushort* __restrict__ dtc)
{
  int i = blockIdx.x * 256 + threadIdx.x;
  if (i >= BL * RR) return;
  int m = i >> 5, r = i & 31;
  dtc[i] = f2b(dbc[m * 160 + r]);
}

// ---------------------------------------------------------------- selective scan (wave per (b,d), lane = n)
__global__ __launch_bounds__(256) void mamba_scan(
    const float* __restrict__ dtf, const float* __restrict__ uf,
    const float* __restrict__ dbc, const float* __restrict__ alog,
    const float* __restrict__ dpar, const float* __restrict__ xz,
    ushort* __restrict__ ymb)
{
  int wid = blockIdx.x * 4 + (threadIdx.x >> 6);
  int n = threadIdx.x & 63;
  int b = wid >> 10, d = wid & (DIN - 1);
  float An = -__expf(alog[d * NS + n]);
  float Dv = dpar[d];
  float h = 0.f;
  size_t tb = (size_t)b * LL;

  float dt = dtf[tb * DIN + d];
  float uv = uf[tb * DIN + d];
  float Bt = dbc[tb * 160 + 32 + n];
  float Ct = dbc[tb * 160 + 96 + n];

  for (int t = 0; t < LL; t++) {
    float dtn = 0.f, un = 0.f, Bn = 0.f, Cn = 0.f;
    if (t + 1 < LL) {
      size_t nb = tb + t + 1;
      dtn = dtf[nb * DIN + d];
      un  = uf[nb * DIN + d];
      Bn  = dbc[nb * 160 + 32 + n];
      Cn  = dbc[nb * 160 + 96 + n];
    }
    h = __expf(dt * An) * h + (dt * uv) * Bt;
    float y = h * Ct;
    y += __shfl_xor(y, 1);  y += __shfl_xor(y, 2);  y += __shfl_xor(y, 4);
    y += __shfl_xor(y, 8);  y += __shfl_xor(y, 16); y += __shfl_xor(y, 32);
    if (n == 0) {
      float yt = y + uv * Dv;
      float z = xz[(tb + t) * (2 * DIN) + DIN + d];
      float g = z / (1.f + __expf(-z));
      ymb[(tb + t) * DIN + d] = f2b(yt * g);
    }
    dt = dtn; uv = un; Bt = Bn; Ct = Cn;
  }
}

// ---------------------------------------------------------------- residual + LayerNorm
__global__ __launch_bounds__(256) void residual_ln(
    const float* __restrict__ x, const float* __restrict__ at,
    const float* __restrict__ mb, const float* __restrict__ lw,
    const float* __restrict__ lb, float* __restrict__ out)
{
  int row = blockIdx.x * 4 + (threadIdx.x >> 6);
  int l = threadIdx.x & 63;
  size_t base = (size_t)row * DD;
  float h[8];
  float s = 0.f, s2 = 0.f;
  #pragma unroll
  for (int half = 0; half < 2; half++) {
    int c = half * 256 + l * 4;
    float4 xv = *(const float4*)(x + base + c);
    float4 av = *(const float4*)(at + base + c);
    float4 mv = *(const float4*)(mb + base + c);
    float* hp = h + half * 4;
    hp[0] = xv.x + av.x + mv.x;
    hp[1] = xv.y + av.y + mv.y;
    hp[2] = xv.z + av.z + mv.z;
    hp[3] = xv.w + av.w + mv.w;
    #pragma unroll
    for (int j = 0; j < 4; j++) { s += hp[j]; s2 += hp[j] * hp[j]; }
  }
  #pragma unroll
  for (int o = 1; o < 64; o <<= 1) { s += __shfl_xor(s, o); s2 += __shfl_xor(s2, o); }
  float mean = s * (1.f / DD);
  float var = s2 * (1.f / DD) - mean * mean;
  float rs = rsqrtf(var + 1e-5f);
  #pragma unroll
  for (int half = 0; half < 2; half++) {
    int c = half * 256 + l * 4;
    float4 ov;
    ov.x = (h[half*4+0] - mean) * rs * lw[c+0] + lb[c+0];
    ov.y = (h[half*4+1] - mean) * rs * lw[c+1] + lb[c+1];
    ov.z = (h[half*4+2] - mean) * rs * lw[c+2] + lb[c+2];
    ov.w = (h[half*4+3] - mean) * rs * lw[c+3] + lb[c+3];
    *(float4*)(out + base + c) = ov;
  }
}

// ---------------------------------------------------------------- host
extern "C" void kernel_launch(void* const* d_in, const int* in_sizes, int n_in,
                              void* d_out, int out_size, void* d_ws, size_t ws_size,
                              hipStream_t stream) {
  const float* x    = (const float*)d_in[0];
  const float* wq   = (const float*)d_in[1];
  const float* bq   = (const float*)d_in[2];
  const float* wk   = (const float*)d_in[3];
  const float* bk   = (const float*)d_in[4];
  const float* wv   = (const float*)d_in[5];
  const float* bv   = (const float*)d_in[6];
  const float* wo   = (const float*)d_in[7];
  const float* bo   = (const float*)d_in[8];
  const float* inw  = (const float*)d_in[9];
  const float* cw   = (const float*)d_in[10];
  const float* cb   = (const float*)d_in[11];
  const float* xpw  = (const float*)d_in[12];
  const float* dtw  = (const float*)d_in[13];
  const float* dtb  = (const float*)d_in[14];
  const float* alog = (const float*)d_in[15];
  const float* dpar = (const float*)d_in[16];
  const float* opw  = (const float*)d_in[17];
  const float* lnw  = (const float*)d_in[18];
  const float* lnb  = (const float*)d_in[19];

  char* ws = (char*)d_ws;
  size_t off = 0;
  auto alloc = [&](size_t bytes) -> void* {
    void* p = ws + off;
    off += (bytes + 255) & ~(size_t)255;
    return p;
  };

  const size_t BLD = (size_t)BL * DD;      // 2.10M
  const size_t BLDIN = (size_t)BL * DIN;   // 4.19M

  ushort* xf_b   = (ushort*)alloc(BLD * 2);
  ushort* wq_b   = (ushort*)alloc(DD * DD * 2);
  ushort* wk_b   = (ushort*)alloc(DD * DD * 2);
  ushort* wv_b   = (ushort*)alloc(DD * DD * 2);
  ushort* wo_b   = (ushort*)alloc(DD * DD * 2);
  ushort* inw_b  = (ushort*)alloc(2 * DIN * DD * 2);
  ushort* xpw_b  = (ushort*)alloc(160 * DIN * 2);
  ushort* dtw_b  = (ushort*)alloc(DIN * RR * 2);
  ushort* opw_b  = (ushort*)alloc(DD * DIN * 2);
  ushort* q_b    = (ushort*)alloc(BLD * 2);
  ushort* k_b    = (ushort*)alloc(BLD * 2);
  ushort* v_b    = (ushort*)alloc(BLD * 2);
  ushort* ctx_b  = (ushort*)alloc(BLD * 2);
  float*  attn_o = (float*)alloc(BLD * 4);
  float*  xz     = (float*)alloc(BL * (size_t)(2 * DIN) * 4);
  float*  u_f    = (float*)alloc(BLDIN * 4);
  ushort* u_b    = (ushort*)alloc(BLDIN * 2);
  float*  dbc    = (float*)alloc((size_t)BL * 160 * 4);
  ushort* dtc_b  = (ushort*)alloc((size_t)BL * RR * 2);
  float*  dt_f   = (float*)alloc(BLDIN * 4);
  ushort* ym_b   = (ushort*)alloc(BLDIN * 2);
  float*  mamba_o= (float*)alloc(BLD * 4);

  // 1) convert inputs to bf16
  CvtJobs cj;
  cj.src[0] = x;    cj.dst[0] = xf_b;  cj.n[0] = (int)BLD;
  cj.src[1] = wq;   cj.dst[1] = wq_b;  cj.n[1] = DD * DD;
  cj.src[2] = wk;   cj.dst[2] = wk_b;  cj.n[2] = DD * DD;
  cj.src[3] = wv;   cj.dst[3] = wv_b;  cj.n[3] = DD * DD;
  cj.src[4] = wo;   cj.dst[4] = wo_b;  cj.n[4] = DD * DD;
  cj.src[5] = inw;  cj.dst[5] = inw_b; cj.n[5] = 2 * DIN * DD;
  cj.src[6] = xpw;  cj.dst[6] = xpw_b; cj.n[6] = 160 * DIN;
  cj.src[7] = dtw;  cj.dst[7] = dtw_b; cj.n[7] = DIN * RR;
  cj.src[8] = opw;  cj.dst[8] = opw_b; cj.n[8] = DD * DIN;
  cvt_multi<<<dim3(256, 9), 256, 0, stream>>>(cj);

  // 2) q,k,v projections
  gemm_bt<<<dim3(8, 64), 256, 0, stream>>>(xf_b, wq_b, bq, nullptr, q_b, BL, DD, DD, 0);
  gemm_bt<<<dim3(8, 64), 256, 0, stream>>>(xf_b, wk_b, bk, nullptr, k_b, BL, DD, DD, 0);
  gemm_bt<<<dim3(8, 64), 256, 0, stream>>>(xf_b, wv_b, bv, nullptr, v_b, BL, DD, DD, 0);

  // 3) flash attention
  flash_attn<<<dim3(32, HH, BB), 256, 0, stream>>>(q_b, k_b, v_b, ctx_b);

  // 4) output projection
  gemm_bt<<<dim3(8, 64), 256, 0, stream>>>(ctx_b, wo_b, bo, attn_o, nullptr, BL, DD, DD, 0);

  // 5) mamba in_proj
  gemm_bt<<<dim3(32, 64), 256, 0, stream>>>(xf_b, inw_b, nullptr, xz, nullptr, BL, 2 * DIN, DD, 0);

  // 6) depthwise conv + SiLU
  conv_silu<<<dim3(32768), 256, 0, stream>>>(xz, cw, cb, u_f, u_b);

  // 7) x_proj
  gemm_bt<<<dim3(3, 64), 256, 0, stream>>>(u_b, xpw_b, nullptr, dbc, nullptr, BL, 160, DIN, 0);

  // 8) dt slice + dt_proj + softplus
  slice_dt<<<dim3(512), 256, 0, stream>>>(dbc, dtc_b);
  gemm_bt<<<dim3(16, 64), 256, 0, stream>>>(dtc_b, dtw_b, dtb, dt_f, nullptr, BL, DIN, RR, 1);

  // 9) selective scan (+ D skip + SiLU(z) gate, writes bf16)
  mamba_scan<<<dim3(512), 256, 0, stream>>>(dt_f, u_f, dbc, alog, dpar, xz, ym_b);

  // 10) out_proj
  gemm_bt<<<dim3(8, 64), 256, 0, stream>>>(ym_b, opw_b, nullptr, mamba_o, nullptr, BL, DD, DIN, 0);

  // 11) residual + LayerNorm
  residual_ln<<<dim3(1024), 256, 0, stream>>>(x, attn_o, mamba_o, lnw, lnb, (float*)d_out);
}

// Round 2
// 747.969 us; speedup vs baseline: 2.1369x; 2.1369x over previous
//
#include <hip/hip_runtime.h>

typedef __attribute__((ext_vector_type(4))) float f32x4;
typedef __attribute__((ext_vector_type(8))) short short8;

#define DEV static __device__ __forceinline__

DEV ushort f2b(float f) {
  union { float f; unsigned u; } v; v.f = f;
  unsigned r = v.u + 0x7FFF + ((v.u >> 16) & 1);
  return (ushort)(r >> 16);
}

// ---------------------------------------------------------------- constants
#define BB    2
#define LL    2048
#define DD    512
#define HH    8
#define EE    64
#define DIN   1024
#define NS    64
#define RR    32
#define BL    4096            // B*L
#define NCH   16              // scan chunks
#define TC    128             // steps per chunk (LL/NCH)
#define MFMA(a,b,c) __builtin_amdgcn_mfma_f32_16x16x32_bf16((a),(b),(c),0,0,0)

// ---------------------------------------------------------------- f32 -> bf16 multi-convert
struct CvtJobs {
  const float* src[9];
  ushort*      dst[9];
  int          n[9];
};

__global__ __launch_bounds__(256) void cvt_multi(CvtJobs j) {
  int job = blockIdx.y;
  const float* s = j.src[job];
  ushort* d = j.dst[job];
  int n = j.n[job];
  for (int i = blockIdx.x * 256 + threadIdx.x; i < n; i += gridDim.x * 256)
    d[i] = f2b(s[i]);
}

// ---------------------------------------------------------------- generic GEMM: C = A @ W^T (+bias)(+softplus)
// A: [M][K] bf16, W: [N][K] bf16, outF/outB: [M][N]
__global__ __launch_bounds__(256) void gemm_bt(
    const ushort* __restrict__ A, const ushort* __restrict__ W,
    const float* __restrict__ bias, float* __restrict__ outF,
    ushort* __restrict__ outB, int M, int N, int K, int act)
{
  __shared__ ushort As[64][40];
  __shared__ ushort Ws[64][40];
  int m0 = blockIdx.y * 64, n0 = blockIdx.x * 64;
  int tid = threadIdx.x, l = tid & 63, w = tid >> 6;
  int wm = (w >> 1) * 32, wn = (w & 1) * 32;
  int lr = l & 15, kl = (l >> 4) * 8;
  int srow = tid >> 2, sk = (tid & 3) * 8;
  f32x4 acc[2][2] = {};

  for (int k0 = 0; k0 < K; k0 += 32) {
    uint4 av = *(const uint4*)&A[(size_t)(m0 + srow) * K + k0 + sk];
    uint4 wv;
    if (n0 + srow < N) wv = *(const uint4*)&W[(size_t)(n0 + srow) * K + k0 + sk];
    else { wv.x = 0; wv.y = 0; wv.z = 0; wv.w = 0; }
    *(uint4*)&As[srow][sk] = av;
    *(uint4*)&Ws[srow][sk] = wv;
    __syncthreads();
    short8 a0 = *(const short8*)&As[wm + lr][kl];
    short8 a1 = *(const short8*)&As[wm + 16 + lr][kl];
    short8 b0 = *(const short8*)&Ws[wn + lr][kl];
    short8 b1 = *(const short8*)&Ws[wn + 16 + lr][kl];
    acc[0][0] = MFMA(a0, b0, acc[0][0]);
    acc[0][1] = MFMA(a0, b1, acc[0][1]);
    acc[1][0] = MFMA(a1, b0, acc[1][0]);
    acc[1][1] = MFMA(a1, b1, acc[1][1]);
    __syncthreads();
  }

  #pragma unroll
  for (int mi = 0; mi < 2; mi++)
    #pragma unroll
    for (int ni = 0; ni < 2; ni++) {
      int rbase = m0 + wm + mi * 16 + ((l >> 4) << 2);
      int col = n0 + wn + ni * 16 + lr;
      if (col < N) {
        float bval = bias ? bias[col] : 0.f;
        #pragma unroll
        for (int r = 0; r < 4; r++) {
          float v = acc[mi][ni][r] + bval;
          if (act == 1) v = (v > 20.f) ? v : log1pf(__expf(v));
          size_t o = (size_t)(rbase + r) * N + col;
          if (outF) outF[o] = v;
          if (outB) outB[o] = f2b(v);
        }
      }
    }
}

// ---------------------------------------------------------------- flash attention (causal, e=64)
__global__ __launch_bounds__(256) void flash_attn(
    const ushort* __restrict__ qb, const ushort* __restrict__ kb,
    const ushort* __restrict__ vb, ushort* __restrict__ ctx)
{
  __shared__ ushort Qs[64][72];
  __shared__ ushort Ks[64][72];
  __shared__ ushort Vt[64][72];
  __shared__ ushort Ps[64][72];

  int qt = blockIdx.x, h = blockIdx.y, b = blockIdx.z;
  int tid = threadIdx.x, l = tid & 63, w = tid >> 6;
  int w16 = w * 16, lr = l & 15, kl = (l >> 4) * 8;

  // stage Q tile
  for (int i = tid; i < 512; i += 256) {
    int row = i >> 3, c8 = (i & 7) * 8;
    *(uint4*)&Qs[row][c8] =
        *(const uint4*)&qb[((size_t)(b * LL + qt * 64 + row)) * DD + h * EE + c8];
  }
  __syncthreads();

  float m_r[4] = {-1e30f, -1e30f, -1e30f, -1e30f};
  float l_r[4] = {0.f, 0.f, 0.f, 0.f};
  f32x4 oacc[4] = {};

  for (int kv = 0; kv <= qt; kv++) {
    // stage K tile + transposed V tile
    for (int i = tid; i < 512; i += 256) {
      int s = i >> 3, c8 = (i & 7) * 8;
      *(uint4*)&Ks[s][c8] =
          *(const uint4*)&kb[((size_t)(b * LL + kv * 64 + s)) * DD + h * EE + c8];
      uint4 vv = *(const uint4*)&vb[((size_t)(b * LL + kv * 64 + s)) * DD + h * EE + c8];
      const ushort* pv = (const ushort*)&vv;
      #pragma unroll
      for (int jj = 0; jj < 8; jj++) Vt[c8 + jj][s] = pv[jj];
    }
    __syncthreads();

    // S = Q K^T (strip of 16 rows per wave)
    f32x4 sacc[4] = {};
    #pragma unroll
    for (int kk = 0; kk < 2; kk++) {
      short8 aq = *(const short8*)&Qs[w16 + lr][kk * 32 + kl];
      #pragma unroll
      for (int nt = 0; nt < 4; nt++) {
        short8 bk8 = *(const short8*)&Ks[nt * 16 + lr][kk * 32 + kl];
        sacc[nt] = MFMA(aq, bk8, sacc[nt]);
      }
    }

    bool diag = (kv == qt);
    float scl[4];
    #pragma unroll
    for (int r = 0; r < 4; r++) {
      int rloc = w16 + ((l >> 4) << 2) + r;
      float sv[4];
      #pragma unroll
      for (int nt = 0; nt < 4; nt++) {
        float v = sacc[nt][r] * 0.125f;
        if (diag && (nt * 16 + lr) > rloc) v = -1e30f;
        sv[nt] = v;
      }
      float mx = fmaxf(fmaxf(sv[0], sv[1]), fmaxf(sv[2], sv[3]));
      #pragma unroll
      for (int o = 1; o < 16; o <<= 1) mx = fmaxf(mx, __shfl_xor(mx, o));
      float mnew = fmaxf(m_r[r], mx);
      float sc = __expf(m_r[r] - mnew);
      float rs = 0.f;
      #pragma unroll
      for (int nt = 0; nt < 4; nt++) {
        float p = __expf(sv[nt] - mnew);
        rs += p;
        Ps[rloc][nt * 16 + lr] = f2b(p);
      }
      #pragma unroll
      for (int o = 1; o < 16; o <<= 1) rs += __shfl_xor(rs, o);
      l_r[r] = l_r[r] * sc + rs;
      m_r[r] = mnew;
      scl[r] = sc;
    }
    #pragma unroll
    for (int nt = 0; nt < 4; nt++)
      #pragma unroll
      for (int r = 0; r < 4; r++) oacc[nt][r] *= scl[r];

    // O += P @ V  (Vt is [e][s])
    #pragma unroll
    for (int kk = 0; kk < 2; kk++) {
      short8 ap = *(const short8*)&Ps[w16 + lr][kk * 32 + kl];
      #pragma unroll
      for (int nt = 0; nt < 4; nt++) {
        short8 bv8 = *(const short8*)&Vt[nt * 16 + lr][kk * 32 + kl];
        oacc[nt] = MFMA(ap, bv8, oacc[nt]);
      }
    }
    __syncthreads();
  }

  #pragma unroll
  for (int nt = 0; nt < 4; nt++)
    #pragma unroll
    for (int r = 0; r < 4; r++) {
      int row = qt * 64 + w16 + ((l >> 4) << 2) + r;
      float v = oacc[nt][r] / l_r[r];
      ctx[((size_t)(b * LL + row)) * DD + h * EE + nt * 16 + lr] = f2b(v);
    }
}

// ---------------------------------------------------------------- depthwise causal conv (K=4) + SiLU (+ SiLU(z) gate precompute)
__global__ __launch_bounds__(256) void conv_silu(
    const float* __restrict__ xz, const float* __restrict__ cw,
    const float* __restrict__ cb, float* __restrict__ u, ushort* __restrict__ ub,
    float* __restrict__ gz)
{
  int i = blockIdx.x * 256 + threadIdx.x;
  if (i >= BL * DIN) return;
  int d = i & (DIN - 1);
  int bl = i >> 10;
  int t = bl & (LL - 1);
  int b = bl >> 11;
  float s = cb[d];
  #pragma unroll
  for (int j = 0; j < 4; j++) {
    int tt = t - 3 + j;
    if (tt >= 0) s += xz[((size_t)(b * LL + tt)) * (2 * DIN) + d] * cw[d * 4 + j];
  }
  float r = s / (1.f + __expf(-s));
  u[i] = r;
  ub[i] = f2b(r);
  float z = xz[(size_t)bl * (2 * DIN) + DIN + d];
  gz[i] = z / (1.f + __expf(-z));
}

// ---------------------------------------------------------------- slice dbc[:, :32] -> bf16
__global__ __launch_bounds__(256) void slice_dt(
    const float* __restrict__ dbc, ushort* __restrict__ dtc)
{
  int i = blockIdx.x * 256 + threadIdx.x;
  if (i >= BL * RR) return;
  int m = i >> 5, r = i & 31;
  dtc[i] = f2b(dbc[m * 160 + r]);
}

// ---------------------------------------------------------------- chunked scan, phase 1: per-chunk h_final and A_prod (h0 = 0)
// wave per (b, d, chunk); lane = n
__global__ __launch_bounds__(256) void scan_phase1(
    const float* __restrict__ dtf, const float* __restrict__ uf,
    const float* __restrict__ dbc, const float* __restrict__ alog,
    float* __restrict__ hf, float* __restrict__ ap)
{
  int wid = blockIdx.x * 4 + (threadIdx.x >> 6);
  int n = threadIdx.x & 63;
  int c = wid & (NCH - 1);
  int d = (wid >> 4) & (DIN - 1);
  int b = wid >> 14;
  float An = -__expf(alog[d * NS + n]);
  float h = 0.f, P = 1.f;
  size_t t0 = (size_t)b * LL + c * TC;

  float dt = dtf[t0 * DIN + d];
  float uv = uf[t0 * DIN + d];
  float Bt = dbc[t0 * 160 + 32 + n];

  for (int t = 0; t < TC; t++) {
    float dtn = 0.f, un = 0.f, Bn = 0.f;
    if (t + 1 < TC) {
      size_t nb = t0 + t + 1;
      dtn = dtf[nb * DIN + d];
      un  = uf[nb * DIN + d];
      Bn  = dbc[nb * 160 + 32 + n];
    }
    float a = __expf(dt * An);
    h = a * h + (dt * uv) * Bt;
    P *= a;
    dt = dtn; uv = un; Bt = Bn;
  }
  size_t o = (((size_t)((b << 10) + d) * NCH) + c) * 64 + n;
  hf[o] = h;
  ap[o] = P;
}

// ---------------------------------------------------------------- chunked scan, phase 2: combine carries across chunks
__global__ __launch_bounds__(256) void scan_carry(
    const float* __restrict__ hf, const float* __restrict__ ap,
    float* __restrict__ carry)
{
  int i = blockIdx.x * 256 + threadIdx.x;   // (b, d, n)
  int n = i & 63;
  int d = (i >> 6) & (DIN - 1);
  int b = i >> 16;
  size_t base = ((size_t)((b << 10) + d) * NCH) * 64 + n;
  float cur = 0.f;
  #pragma unroll
  for (int c = 0; c < NCH; c++) {
    carry[base + (size_t)c * 64] = cur;
    cur = ap[base + (size_t)c * 64] * cur + hf[base + (size_t)c * 64];
  }
}

// ---------------------------------------------------------------- chunked scan, phase 3: full scan with carry, y output (+D skip, gate)
__global__ __launch_bounds__(256) void scan_phase3(
    const float* __restrict__ dtf, const float* __restrict__ uf,
    const float* __restrict__ dbc, const float* __restrict__ alog,
    const float* __restrict__ dpar, const float* __restrict__ gz,
    const float* __restrict__ carry, ushort* __restrict__ ymb)
{
  int wid = blockIdx.x * 4 + (threadIdx.x >> 6);
  int n = threadIdx.x & 63;
  int c = wid & (NCH - 1);
  int d = (wid >> 4) & (DIN - 1);
  int b = wid >> 14;
  float An = -__expf(alog[d * NS + n]);
  float Dv = dpar[d];
  float h = carry[(((size_t)((b << 10) + d) * NCH) + c) * 64 + n];
  size_t t0 = (size_t)b * LL + c * TC;

  float dt = dtf[t0 * DIN + d];
  float uv = uf[t0 * DIN + d];
  float Bt = dbc[t0 * 160 + 32 + n];
  float Ct = dbc[t0 * 160 + 96 + n];

  for (int t = 0; t < TC; t++) {
    float dtn = 0.f, un = 0.f, Bn = 0.f, Cn = 0.f;
    if (t + 1 < TC) {
      size_t nb = t0 + t + 1;
      dtn = dtf[nb * DIN + d];
      un  = uf[nb * DIN + d];
      Bn  = dbc[nb * 160 + 32 + n];
      Cn  = dbc[nb * 160 + 96 + n];
    }
    float a = __expf(dt * An);
    h = a * h + (dt * uv) * Bt;
    float y = h * Ct;
    y += __shfl_xor(y, 1);  y += __shfl_xor(y, 2);  y += __shfl_xor(y, 4);
    y += __shfl_xor(y, 8);  y += __shfl_xor(y, 16); y += __shfl_xor(y, 32);
    if (n == 0) {
      float yt = (y + uv * Dv) * gz[(t0 + t) * DIN + d];
      ymb[(t0 + t) * DIN + d] = f2b(yt);
    }
    dt = dtn; uv = un; Bt = Bn; Ct = Cn;
  }
}

// ---------------------------------------------------------------- residual + LayerNorm
__global__ __launch_bounds__(256) void residual_ln(
    const float* __restrict__ x, const float* __restrict__ at,
    const float* __restrict__ mb, const float* __restrict__ lw,
    const float* __restrict__ lb, float* __restrict__ out)
{
  int row = blockIdx.x * 4 + (threadIdx.x >> 6);
  int l = threadIdx.x & 63;
  size_t base = (size_t)row * DD;
  float h[8];
  float s = 0.f, s2 = 0.f;
  #pragma unroll
  for (int half = 0; half < 2; half++) {
    int c = half * 256 + l * 4;
    float4 xv = *(const float4*)(x + base + c);
    float4 av = *(const float4*)(at + base + c);
    float4 mv = *(const float4*)(mb + base + c);
    float* hp = h + half * 4;
    hp[0] = xv.x + av.x + mv.x;
    hp[1] = xv.y + av.y + mv.y;
    hp[2] = xv.z + av.z + mv.z;
    hp[3] = xv.w + av.w + mv.w;
    #pragma unroll
    for (int j = 0; j < 4; j++) { s += hp[j]; s2 += hp[j] * hp[j]; }
  }
  #pragma unroll
  for (int o = 1; o < 64; o <<= 1) { s += __shfl_xor(s, o); s2 += __shfl_xor(s2, o); }
  float mean = s * (1.f / DD);
  float var = s2 * (1.f / DD) - mean * mean;
  float rs = rsqrtf(var + 1e-5f);
  #pragma unroll
  for (int half = 0; half < 2; half++) {
    int c = half * 256 + l * 4;
    float4 ov;
    ov.x = (h[half*4+0] - mean) * rs * lw[c+0] + lb[c+0];
    ov.y = (h[half*4+1] - mean) * rs * lw[c+1] + lb[c+1];
    ov.z = (h[half*4+2] - mean) * rs * lw[c+2] + lb[c+2];
    ov.w = (h[half*4+3] - mean) * rs * lw[c+3] + lb[c+3];
    *(float4*)(out + base + c) = ov;
  }
}

// ---------------------------------------------------------------- host
extern "C" void kernel_launch(void* const* d_in, const int* in_sizes, int n_in,
                              void* d_out, int out_size, void* d_ws, size_t ws_size,
                              hipStream_t stream) {
  const float* x    = (const float*)d_in[0];
  const float* wq   = (const float*)d_in[1];
  const float* bq   = (const float*)d_in[2];
  const float* wk   = (const float*)d_in[3];
  const float* bk   = (const float*)d_in[4];
  const float* wv   = (const float*)d_in[5];
  const float* bv   = (const float*)d_in[6];
  const float* wo   = (const float*)d_in[7];
  const float* bo   = (const float*)d_in[8];
  const float* inw  = (const float*)d_in[9];
  const float* cw   = (const float*)d_in[10];
  const float* cb   = (const float*)d_in[11];
  const float* xpw  = (const float*)d_in[12];
  const float* dtw  = (const float*)d_in[13];
  const float* dtb  = (const float*)d_in[14];
  const float* alog = (const float*)d_in[15];
  const float* dpar = (const float*)d_in[16];
  const float* opw  = (const float*)d_in[17];
  const float* lnw  = (const float*)d_in[18];
  const float* lnb  = (const float*)d_in[19];

  char* ws = (char*)d_ws;
  size_t off = 0;
  auto alloc = [&](size_t bytes) -> void* {
    void* p = ws + off;
    off += (bytes + 255) & ~(size_t)255;
    return p;
  };

  const size_t BLD = (size_t)BL * DD;      // 2.10M
  const size_t BLDIN = (size_t)BL * DIN;   // 4.19M

  ushort* xf_b   = (ushort*)alloc(BLD * 2);
  ushort* wq_b   = (ushort*)alloc(DD * DD * 2);
  ushort* wk_b   = (ushort*)alloc(DD * DD * 2);
  ushort* wv_b   = (ushort*)alloc(DD * DD * 2);
  ushort* wo_b   = (ushort*)alloc(DD * DD * 2);
  ushort* inw_b  = (ushort*)alloc(2 * DIN * DD * 2);
  ushort* xpw_b  = (ushort*)alloc(160 * DIN * 2);
  ushort* dtw_b  = (ushort*)alloc(DIN * RR * 2);
  ushort* opw_b  = (ushort*)alloc(DD * DIN * 2);
  ushort* q_b    = (ushort*)alloc(BLD * 2);
  ushort* k_b    = (ushort*)alloc(BLD * 2);
  ushort* v_b    = (ushort*)alloc(BLD * 2);
  ushort* ctx_b  = (ushort*)alloc(BLD * 2);
  float*  attn_o = (float*)alloc(BLD * 4);
  float*  xz     = (float*)alloc(BL * (size_t)(2 * DIN) * 4);
  float*  u_f    = (float*)alloc(BLDIN * 4);
  ushort* u_b    = (ushort*)alloc(BLDIN * 2);
  float*  dbc    = (float*)alloc((size_t)BL * 160 * 4);
  ushort* dtc_b  = (ushort*)alloc((size_t)BL * RR * 2);
  float*  dt_f   = (float*)alloc(BLDIN * 4);
  ushort* ym_b   = (ushort*)alloc(BLDIN * 2);
  float*  mamba_o= (float*)alloc(BLD * 4);
  float*  gz_f   = (float*)alloc(BLDIN * 4);

  // scan scratch aliased onto xz (dead after conv_silu; scan runs later)
  const size_t SCN = (size_t)BB * DIN * NCH * 64;   // 2.1M elems
  float* hf_s    = (float*)xz;
  float* ap_s    = hf_s + SCN;
  float* carry_s = ap_s + SCN;

  // 1) convert inputs to bf16
  CvtJobs cj;
  cj.src[0] = x;    cj.dst[0] = xf_b;  cj.n[0] = (int)BLD;
  cj.src[1] = wq;   cj.dst[1] = wq_b;  cj.n[1] = DD * DD;
  cj.src[2] = wk;   cj.dst[2] = wk_b;  cj.n[2] = DD * DD;
  cj.src[3] = wv;   cj.dst[3] = wv_b;  cj.n[3] = DD * DD;
  cj.src[4] = wo;   cj.dst[4] = wo_b;  cj.n[4] = DD * DD;
  cj.src[5] = inw;  cj.dst[5] = inw_b; cj.n[5] = 2 * DIN * DD;
  cj.src[6] = xpw;  cj.dst[6] = xpw_b; cj.n[6] = 160 * DIN;
  cj.src[7] = dtw;  cj.dst[7] = dtw_b; cj.n[7] = DIN * RR;
  cj.src[8] = opw;  cj.dst[8] = opw_b; cj.n[8] = DD * DIN;
  cvt_multi<<<dim3(256, 9), 256, 0, stream>>>(cj);

  // 2) q,k,v projections
  gemm_bt<<<dim3(8, 64), 256, 0, stream>>>(xf_b, wq_b, bq, nullptr, q_b, BL, DD, DD, 0);
  gemm_bt<<<dim3(8, 64), 256, 0, stream>>>(xf_b, wk_b, bk, nullptr, k_b, BL, DD, DD, 0);
  gemm_bt<<<dim3(8, 64), 256, 0, stream>>>(xf_b, wv_b, bv, nullptr, v_b, BL, DD, DD, 0);

  // 3) flash attention
  flash_attn<<<dim3(32, HH, BB), 256, 0, stream>>>(q_b, k_b, v_b, ctx_b);

  // 4) output projection
  gemm_bt<<<dim3(8, 64), 256, 0, stream>>>(ctx_b, wo_b, bo, attn_o, nullptr, BL, DD, DD, 0);

  // 5) mamba in_proj
  gemm_bt<<<dim3(32, 64), 256, 0, stream>>>(xf_b, inw_b, nullptr, xz, nullptr, BL, 2 * DIN, DD, 0);

  // 6) depthwise conv + SiLU (+ gate precompute)
  conv_silu<<<dim3(32768), 256, 0, stream>>>(xz, cw, cb, u_f, u_b, gz_f);

  // 7) x_proj
  gemm_bt<<<dim3(3, 64), 256, 0, stream>>>(u_b, xpw_b, nullptr, dbc, nullptr, BL, 160, DIN, 0);

  // 8) dt slice + dt_proj + softplus
  slice_dt<<<dim3(512), 256, 0, stream>>>(dbc, dtc_b);
  gemm_bt<<<dim3(16, 64), 256, 0, stream>>>(dtc_b, dtw_b, dtb, dt_f, nullptr, BL, DIN, RR, 1);

  // 9) chunked selective scan (xz is dead now; hf/ap/carry alias it)
  scan_phase1<<<dim3(8192), 256, 0, stream>>>(dt_f, u_f, dbc, alog, hf_s, ap_s);
  scan_carry<<<dim3(512), 256, 0, stream>>>(hf_s, ap_s, carry_s);
  scan_phase3<<<dim3(8192), 256, 0, stream>>>(dt_f, u_f, dbc, alog, dpar, gz_f, carry_s, ym_b);

  // 10) out_proj
  gemm_bt<<<dim3(8, 64), 256, 0, stream>>>(ym_b, opw_b, nullptr, mamba_o, nullptr, BL, DD, DIN, 0);

  // 11) residual + LayerNorm
  residual_ln<<<dim3(1024), 256, 0, stream>>>(x, attn_o, mamba_o, lnw, lnb, (float*)d_out);
}

// Round 3
// 690.866 us; speedup vs baseline: 2.3135x; 1.0827x over previous
//
#include <hip/hip_runtime.h>

typedef __attribute__((ext_vector_type(4))) float f32x4;
typedef __attribute__((ext_vector_type(8))) short short8;

#define DEV static __device__ __forceinline__

DEV ushort f2b(float f) {
  union { float f; unsigned u; } v; v.f = f;
  unsigned r = v.u + 0x7FFF + ((v.u >> 16) & 1);
  return (ushort)(r >> 16);
}

// DPP-based wave64 sum: result lands in lane 63. VALU-pipe only (no LDS).
#define DPP_ADD(x, ctrl, rmask) \
  ((x) + __int_as_float(__builtin_amdgcn_update_dpp(0, __float_as_int(x), (ctrl), (rmask), 0xf, false)))

// ---------------------------------------------------------------- constants
#define BB    2
#define LL    2048
#define DD    512
#define HH    8
#define EE    64
#define DIN   1024
#define NS    64
#define RR    32
#define BL    4096            // B*L
#define NCH   16              // scan chunks
#define TC    128             // steps per chunk (LL/NCH)
#define MFMA(a,b,c) __builtin_amdgcn_mfma_f32_16x16x32_bf16((a),(b),(c),0,0,0)

// ---------------------------------------------------------------- f32 -> bf16 multi-convert
struct CvtJobs {
  const float* src[9];
  ushort*      dst[9];
  int          n[9];
};

__global__ __launch_bounds__(256) void cvt_multi(CvtJobs j) {
  int job = blockIdx.y;
  const float* s = j.src[job];
  ushort* d = j.dst[job];
  int n = j.n[job];
  for (int i = blockIdx.x * 256 + threadIdx.x; i < n; i += gridDim.x * 256)
    d[i] = f2b(s[i]);
}

// ---------------------------------------------------------------- generic GEMM: C = A @ W^T (+bias)(+softplus)
// A: [M][K] bf16, W: [N][K] bf16, outF/outB: [M][N]
__global__ __launch_bounds__(256) void gemm_bt(
    const ushort* __restrict__ A, const ushort* __restrict__ W,
    const float* __restrict__ bias, float* __restrict__ outF,
    ushort* __restrict__ outB, int M, int N, int K, int act)
{
  __shared__ ushort As[64][40];
  __shared__ ushort Ws[64][40];
  int m0 = blockIdx.y * 64, n0 = blockIdx.x * 64;
  int tid = threadIdx.x, l = tid & 63, w = tid >> 6;
  int wm = (w >> 1) * 32, wn = (w & 1) * 32;
  int lr = l & 15, kl = (l >> 4) * 8;
  int srow = tid >> 2, sk = (tid & 3) * 8;
  f32x4 acc[2][2] = {};

  for (int k0 = 0; k0 < K; k0 += 32) {
    uint4 av = *(const uint4*)&A[(size_t)(m0 + srow) * K + k0 + sk];
    uint4 wv;
    if (n0 + srow < N) wv = *(const uint4*)&W[(size_t)(n0 + srow) * K + k0 + sk];
    else { wv.x = 0; wv.y = 0; wv.z = 0; wv.w = 0; }
    *(uint4*)&As[srow][sk] = av;
    *(uint4*)&Ws[srow][sk] = wv;
    __syncthreads();
    short8 a0 = *(const short8*)&As[wm + lr][kl];
    short8 a1 = *(const short8*)&As[wm + 16 + lr][kl];
    short8 b0 = *(const short8*)&Ws[wn + lr][kl];
    short8 b1 = *(const short8*)&Ws[wn + 16 + lr][kl];
    acc[0][0] = MFMA(a0, b0, acc[0][0]);
    acc[0][1] = MFMA(a0, b1, acc[0][1]);
    acc[1][0] = MFMA(a1, b0, acc[1][0]);
    acc[1][1] = MFMA(a1, b1, acc[1][1]);
    __syncthreads();
  }

  #pragma unroll
  for (int mi = 0; mi < 2; mi++)
    #pragma unroll
    for (int ni = 0; ni < 2; ni++) {
      int rbase = m0 + wm + mi * 16 + ((l >> 4) << 2);
      int col = n0 + wn + ni * 16 + lr;
      if (col < N) {
        float bval = bias ? bias[col] : 0.f;
        #pragma unroll
        for (int r = 0; r < 4; r++) {
          float v = acc[mi][ni][r] + bval;
          if (act == 1) v = (v > 20.f) ? v : log1pf(__expf(v));
          size_t o = (size_t)(rbase + r) * N + col;
          if (outF) outF[o] = v;
          if (outB) outB[o] = f2b(v);
        }
      }
    }
}

// ---------------------------------------------------------------- flash attention (causal, e=64)
__global__ __launch_bounds__(256) void flash_attn(
    const ushort* __restrict__ qb, const ushort* __restrict__ kb,
    const ushort* __restrict__ vb, ushort* __restrict__ ctx)
{
  __shared__ ushort Qs[64][72];
  __shared__ ushort Ks[64][72];
  __shared__ ushort Vt[64][72];
  __shared__ ushort Ps[64][72];

  int qt = blockIdx.x, h = blockIdx.y, b = blockIdx.z;
  int tid = threadIdx.x, l = tid & 63, w = tid >> 6;
  int w16 = w * 16, lr = l & 15, kl = (l >> 4) * 8;

  // stage Q tile
  for (int i = tid; i < 512; i += 256) {
    int row = i >> 3, c8 = (i & 7) * 8;
    *(uint4*)&Qs[row][c8] =
        *(const uint4*)&qb[((size_t)(b * LL + qt * 64 + row)) * DD + h * EE + c8];
  }
  __syncthreads();

  float m_r[4] = {-1e30f, -1e30f, -1e30f, -1e30f};
  float l_r[4] = {0.f, 0.f, 0.f, 0.f};
  f32x4 oacc[4] = {};

  for (int kv = 0; kv <= qt; kv++) {
    // stage K tile + transposed V tile
    for (int i = tid; i < 512; i += 256) {
      int s = i >> 3, c8 = (i & 7) * 8;
      *(uint4*)&Ks[s][c8] =
          *(const uint4*)&kb[((size_t)(b * LL + kv * 64 + s)) * DD + h * EE + c8];
      uint4 vv = *(const uint4*)&vb[((size_t)(b * LL + kv * 64 + s)) * DD + h * EE + c8];
      const ushort* pv = (const ushort*)&vv;
      #pragma unroll
      for (int jj = 0; jj < 8; jj++) Vt[c8 + jj][s] = pv[jj];
    }
    __syncthreads();

    // S = Q K^T (strip of 16 rows per wave)
    f32x4 sacc[4] = {};
    #pragma unroll
    for (int kk = 0; kk < 2; kk++) {
      short8 aq = *(const short8*)&Qs[w16 + lr][kk * 32 + kl];
      #pragma unroll
      for (int nt = 0; nt < 4; nt++) {
        short8 bk8 = *(const short8*)&Ks[nt * 16 + lr][kk * 32 + kl];
        sacc[nt] = MFMA(aq, bk8, sacc[nt]);
      }
    }

    bool diag = (kv == qt);
    float scl[4];
    #pragma unroll
    for (int r = 0; r < 4; r++) {
      int rloc = w16 + ((l >> 4) << 2) + r;
      float sv[4];
      #pragma unroll
      for (int nt = 0; nt < 4; nt++) {
        float v = sacc[nt][r] * 0.125f;
        if (diag && (nt * 16 + lr) > rloc) v = -1e30f;
        sv[nt] = v;
      }
      float mx = fmaxf(fmaxf(sv[0], sv[1]), fmaxf(sv[2], sv[3]));
      #pragma unroll
      for (int o = 1; o < 16; o <<= 1) mx = fmaxf(mx, __shfl_xor(mx, o));
      float mnew = fmaxf(m_r[r], mx);
      float sc = __expf(m_r[r] - mnew);
      float rs = 0.f;
      #pragma unroll
      for (int nt = 0; nt < 4; nt++) {
        float p = __expf(sv[nt] - mnew);
        rs += p;
        Ps[rloc][nt * 16 + lr] = f2b(p);
      }
      #pragma unroll
      for (int o = 1; o < 16; o <<= 1) rs += __shfl_xor(rs, o);
      l_r[r] = l_r[r] * sc + rs;
      m_r[r] = mnew;
      scl[r] = sc;
    }
    #pragma unroll
    for (int nt = 0; nt < 4; nt++)
      #pragma unroll
      for (int r = 0; r < 4; r++) oacc[nt][r] *= scl[r];

    // O += P @ V  (Vt is [e][s])
    #pragma unroll
    for (int kk = 0; kk < 2; kk++) {
      short8 ap = *(const short8*)&Ps[w16 + lr][kk * 32 + kl];
      #pragma unroll
      for (int nt = 0; nt < 4; nt++) {
        short8 bv8 = *(const short8*)&Vt[nt * 16 + lr][kk * 32 + kl];
        oacc[nt] = MFMA(ap, bv8, oacc[nt]);
      }
    }
    __syncthreads();
  }

  #pragma unroll
  for (int nt = 0; nt < 4; nt++)
    #pragma unroll
    for (int r = 0; r < 4; r++) {
      int row = qt * 64 + w16 + ((l >> 4) << 2) + r;
      float v = oacc[nt][r] / l_r[r];
      ctx[((size_t)(b * LL + row)) * DD + h * EE + nt * 16 + lr] = f2b(v);
    }
}

// ---------------------------------------------------------------- depthwise causal conv (K=4) + SiLU (+ SiLU(z) gate precompute)
__global__ __launch_bounds__(256) void conv_silu(
    const float* __restrict__ xz, const float* __restrict__ cw,
    const float* __restrict__ cb, float* __restrict__ u, ushort* __restrict__ ub,
    float* __restrict__ gz)
{
  int i = blockIdx.x * 256 + threadIdx.x;
  if (i >= BL * DIN) return;
  int d = i & (DIN - 1);
  int bl = i >> 10;
  int t = bl & (LL - 1);
  int b = bl >> 11;
  float s = cb[d];
  #pragma unroll
  for (int j = 0; j < 4; j++) {
    int tt = t - 3 + j;
    if (tt >= 0) s += xz[((size_t)(b * LL + tt)) * (2 * DIN) + d] * cw[d * 4 + j];
  }
  float r = s / (1.f + __expf(-s));
  u[i] = r;
  ub[i] = f2b(r);
  float z = xz[(size_t)bl * (2 * DIN) + DIN + d];
  gz[i] = z / (1.f + __expf(-z));
}

// ---------------------------------------------------------------- slice dbc[:, :32] -> bf16
__global__ __launch_bounds__(256) void slice_dt(
    const float* __restrict__ dbc, ushort* __restrict__ dtc)
{
  int i = blockIdx.x * 256 + threadIdx.x;
  if (i >= BL * RR) return;
  int m = i >> 5, r = i & 31;
  dtc[i] = f2b(dbc[m * 160 + r]);
}

// ---------------------------------------------------------------- chunked scan, phase 1: per-chunk h_final and A_prod (h0 = 0)
// wave per (b, d, chunk); lane = n
__global__ __launch_bounds__(256) void scan_phase1(
    const float* __restrict__ dtf, const float* __restrict__ uf,
    const float* __restrict__ dbc, const float* __restrict__ alog,
    float* __restrict__ hf, float* __restrict__ ap)
{
  int wid = blockIdx.x * 4 + (threadIdx.x >> 6);
  int n = threadIdx.x & 63;
  int c = wid & (NCH - 1);
  int d = (wid >> 4) & (DIN - 1);
  int b = wid >> 14;
  float An = -__expf(alog[d * NS + n]);
  float h = 0.f, S = 0.f;
  size_t t0 = (size_t)b * LL + c * TC;

  float dt = dtf[t0 * DIN + d];
  float uv = uf[t0 * DIN + d];
  float Bt = dbc[t0 * 160 + 32 + n];

  for (int t = 0; t < TC; t++) {
    float dtn = 0.f, un = 0.f, Bn = 0.f;
    if (t + 1 < TC) {
      size_t nb = t0 + t + 1;
      dtn = dtf[nb * DIN + d];
      un  = uf[nb * DIN + d];
      Bn  = dbc[nb * 160 + 32 + n];
    }
    float a = __expf(dt * An);
    h = a * h + (dt * uv) * Bt;
    S += dt;
    dt = dtn; uv = un; Bt = Bn;
  }
  size_t o = (((size_t)((b << 10) + d) * NCH) + c) * 64 + n;
  hf[o] = h;
  ap[o] = __expf(S * An);   // prod of exp(dt*An) == exp(An * sum dt)
}

// ---------------------------------------------------------------- chunked scan, phase 2: combine carries across chunks
__global__ __launch_bounds__(256) void scan_carry(
    const float* __restrict__ hf, const float* __restrict__ ap,
    float* __restrict__ carry)
{
  int i = blockIdx.x * 256 + threadIdx.x;   // (b, d, n)
  int n = i & 63;
  int d = (i >> 6) & (DIN - 1);
  int b = i >> 16;
  size_t base = ((size_t)((b << 10) + d) * NCH) * 64 + n;
  float cur = 0.f;
  #pragma unroll
  for (int c = 0; c < NCH; c++) {
    carry[base + (size_t)c * 64] = cur;
    cur = ap[base + (size_t)c * 64] * cur + hf[base + (size_t)c * 64];
  }
}

// ---------------------------------------------------------------- chunked scan, phase 3: full scan with carry, y output (+D skip, gate)
__global__ __launch_bounds__(256) void scan_phase3(
    const float* __restrict__ dtf, const float* __restrict__ uf,
    const float* __restrict__ dbc, const float* __restrict__ alog,
    const float* __restrict__ dpar, const float* __restrict__ gz,
    const float* __restrict__ carry, ushort* __restrict__ ymb)
{
  int wid = blockIdx.x * 4 + (threadIdx.x >> 6);
  int n = threadIdx.x & 63;
  int c = wid & (NCH - 1);
  int d = (wid >> 4) & (DIN - 1);
  int b = wid >> 14;
  float An = -__expf(alog[d * NS + n]);
  float Dv = dpar[d];
  float h = carry[(((size_t)((b << 10) + d) * NCH) + c) * 64 + n];
  size_t t0 = (size_t)b * LL + c * TC;

  float dt = dtf[t0 * DIN + d];
  float uv = uf[t0 * DIN + d];
  float Bt = dbc[t0 * 160 + 32 + n];
  float Ct = dbc[t0 * 160 + 96 + n];

  for (int t = 0; t < TC; t++) {
    float dtn = 0.f, un = 0.f, Bn = 0.f, Cn = 0.f;
    if (t + 1 < TC) {
      size_t nb = t0 + t + 1;
      dtn = dtf[nb * DIN + d];
      un  = uf[nb * DIN + d];
      Bn  = dbc[nb * 160 + 32 + n];
      Cn  = dbc[nb * 160 + 96 + n];
    }
    float a = __expf(dt * An);
    h = a * h + (dt * uv) * Bt;
    float y = h * Ct;
    // wave64 sum via DPP (VALU pipe, no LDS): result in lane 63
    y = DPP_ADD(y, 0x111, 0xf);   // row_shr:1
    y = DPP_ADD(y, 0x112, 0xf);   // row_shr:2
    y = DPP_ADD(y, 0x114, 0xf);   // row_shr:4
    y = DPP_ADD(y, 0x118, 0xf);   // row_shr:8
    y = DPP_ADD(y, 0x142, 0xa);   // row_bcast:15 -> rows 1,3
    y = DPP_ADD(y, 0x143, 0xc);   // row_bcast:31 -> rows 2,3
    if (n == 63) {
      float yt = (y + uv * Dv) * gz[(t0 + t) * DIN + d];
      ymb[(t0 + t) * DIN + d] = f2b(yt);
    }
    dt = dtn; uv = un; Bt = Bn; Ct = Cn;
  }
}

// ---------------------------------------------------------------- residual + LayerNorm
__global__ __launch_bounds__(256) void residual_ln(
    const float* __restrict__ x, const float* __restrict__ at,
    const float* __restrict__ mb, const float* __restrict__ lw,
    const float* __restrict__ lb, float* __restrict__ out)
{
  int row = blockIdx.x * 4 + (threadIdx.x >> 6);
  int l = threadIdx.x & 63;
  size_t base = (size_t)row * DD;
  float h[8];
  float s = 0.f, s2 = 0.f;
  #pragma unroll
  for (int half = 0; half < 2; half++) {
    int c = half * 256 + l * 4;
    float4 xv = *(const float4*)(x + base + c);
    float4 av = *(const float4*)(at + base + c);
    float4 mv = *(const float4*)(mb + base + c);
    float* hp = h + half * 4;
    hp[0] = xv.x + av.x + mv.x;
    hp[1] = xv.y + av.y + mv.y;
    hp[2] = xv.z + av.z + mv.z;
    hp[3] = xv.w + av.w + mv.w;
    #pragma unroll
    for (int j = 0; j < 4; j++) { s += hp[j]; s2 += hp[j] * hp[j]; }
  }
  #pragma unroll
  for (int o = 1; o < 64; o <<= 1) { s += __shfl_xor(s, o); s2 += __shfl_xor(s2, o); }
  float mean = s * (1.f / DD);
  float var = s2 * (1.f / DD) - mean * mean;
  float rs = rsqrtf(var + 1e-5f);
  #pragma unroll
  for (int half = 0; half < 2; half++) {
    int c = half * 256 + l * 4;
    float4 ov;
    ov.x = (h[half*4+0] - mean) * rs * lw[c+0] + lb[c+0];
    ov.y = (h[half*4+1] - mean) * rs * lw[c+1] + lb[c+1];
    ov.z = (h[half*4+2] - mean) * rs * lw[c+2] + lb[c+2];
    ov.w = (h[half*4+3] - mean) * rs * lw[c+3] + lb[c+3];
    *(float4*)(out + base + c) = ov;
  }
}

// ---------------------------------------------------------------- host
extern "C" void kernel_launch(void* const* d_in, const int* in_sizes, int n_in,
                              void* d_out, int out_size, void* d_ws, size_t ws_size,
                              hipStream_t stream) {
  const float* x    = (const float*)d_in[0];
  const float* wq   = (const float*)d_in[1];
  const float* bq   = (const float*)d_in[2];
  const float* wk   = (const float*)d_in[3];
  const float* bk   = (const float*)d_in[4];
  const float* wv   = (const float*)d_in[5];
  const float* bv   = (const float*)d_in[6];
  const float* wo   = (const float*)d_in[7];
  const float* bo   = (const float*)d_in[8];
  const float* inw  = (const float*)d_in[9];
  const float* cw   = (const float*)d_in[10];
  const float* cb   = (const float*)d_in[11];
  const float* xpw  = (const float*)d_in[12];
  const float* dtw  = (const float*)d_in[13];
  const float* dtb  = (const float*)d_in[14];
  const float* alog = (const float*)d_in[15];
  const float* dpar = (const float*)d_in[16];
  const float* opw  = (const float*)d_in[17];
  const float* lnw  = (const float*)d_in[18];
  const float* lnb  = (const float*)d_in[19];

  char* ws = (char*)d_ws;
  size_t off = 0;
  auto alloc = [&](size_t bytes) -> void* {
    void* p = ws + off;
    off += (bytes + 255) & ~(size_t)255;
    return p;
  };

  const size_t BLD = (size_t)BL * DD;      // 2.10M
  const size_t BLDIN = (size_t)BL * DIN;   // 4.19M

  ushort* xf_b   = (ushort*)alloc(BLD * 2);
  ushort* wq_b   = (ushort*)alloc(DD * DD * 2);
  ushort* wk_b   = (ushort*)alloc(DD * DD * 2);
  ushort* wv_b   = (ushort*)alloc(DD * DD * 2);
  ushort* wo_b   = (ushort*)alloc(DD * DD * 2);
  ushort* inw_b  = (ushort*)alloc(2 * DIN * DD * 2);
  ushort* xpw_b  = (ushort*)alloc(160 * DIN * 2);
  ushort* dtw_b  = (ushort*)alloc(DIN * RR * 2);
  ushort* opw_b  = (ushort*)alloc(DD * DIN * 2);
  ushort* q_b    = (ushort*)alloc(BLD * 2);
  ushort* k_b    = (ushort*)alloc(BLD * 2);
  ushort* v_b    = (ushort*)alloc(BLD * 2);
  ushort* ctx_b  = (ushort*)alloc(BLD * 2);
  float*  attn_o = (float*)alloc(BLD * 4);
  float*  xz     = (float*)alloc(BL * (size_t)(2 * DIN) * 4);
  float*  u_f    = (float*)alloc(BLDIN * 4);
  ushort* u_b    = (ushort*)alloc(BLDIN * 2);
  float*  dbc    = (float*)alloc((size_t)BL * 160 * 4);
  ushort* dtc_b  = (ushort*)alloc((size_t)BL * RR * 2);
  float*  dt_f   = (float*)alloc(BLDIN * 4);
  ushort* ym_b   = (ushort*)alloc(BLDIN * 2);
  float*  mamba_o= (float*)alloc(BLD * 4);
  float*  gz_f   = (float*)alloc(BLDIN * 4);

  // scan scratch aliased onto xz (dead after conv_silu; scan runs later)
  const size_t SCN = (size_t)BB * DIN * NCH * 64;   // 2.1M elems
  float* hf_s    = (float*)xz;
  float* ap_s    = hf_s + SCN;
  float* carry_s = ap_s + SCN;

  // 1) convert inputs to bf16
  CvtJobs cj;
  cj.src[0] = x;    cj.dst[0] = xf_b;  cj.n[0] = (int)BLD;
  cj.src[1] = wq;   cj.dst[1] = wq_b;  cj.n[1] = DD * DD;
  cj.src[2] = wk;   cj.dst[2] = wk_b;  cj.n[2] = DD * DD;
  cj.src[3] = wv;   cj.dst[3] = wv_b;  cj.n[3] = DD * DD;
  cj.src[4] = wo;   cj.dst[4] = wo_b;  cj.n[4] = DD * DD;
  cj.src[5] = inw;  cj.dst[5] = inw_b; cj.n[5] = 2 * DIN * DD;
  cj.src[6] = xpw;  cj.dst[6] = xpw_b; cj.n[6] = 160 * DIN;
  cj.src[7] = dtw;  cj.dst[7] = dtw_b; cj.n[7] = DIN * RR;
  cj.src[8] = opw;  cj.dst[8] = opw_b; cj.n[8] = DD * DIN;
  cvt_multi<<<dim3(256, 9), 256, 0, stream>>>(cj);

  // 2) q,k,v projections
  gemm_bt<<<dim3(8, 64), 256, 0, stream>>>(xf_b, wq_b, bq, nullptr, q_b, BL, DD, DD, 0);
  gemm_bt<<<dim3(8, 64), 256, 0, stream>>>(xf_b, wk_b, bk, nullptr, k_b, BL, DD, DD, 0);
  gemm_bt<<<dim3(8, 64), 256, 0, stream>>>(xf_b, wv_b, bv, nullptr, v_b, BL, DD, DD, 0);

  // 3) flash attention
  flash_attn<<<dim3(32, HH, BB), 256, 0, stream>>>(q_b, k_b, v_b, ctx_b);

  // 4) output projection
  gemm_bt<<<dim3(8, 64), 256, 0, stream>>>(ctx_b, wo_b, bo, attn_o, nullptr, BL, DD, DD, 0);

  // 5) mamba in_proj
  gemm_bt<<<dim3(32, 64), 256, 0, stream>>>(xf_b, inw_b, nullptr, xz, nullptr, BL, 2 * DIN, DD, 0);

  // 6) depthwise conv + SiLU (+ gate precompute)
  conv_silu<<<dim3(32768), 256, 0, stream>>>(xz, cw, cb, u_f, u_b, gz_f);

  // 7) x_proj
  gemm_bt<<<dim3(3, 64), 256, 0, stream>>>(u_b, xpw_b, nullptr, dbc, nullptr, BL, 160, DIN, 0);

  // 8) dt slice + dt_proj + softplus
  slice_dt<<<dim3(512), 256, 0, stream>>>(dbc, dtc_b);
  gemm_bt<<<dim3(16, 64), 256, 0, stream>>>(dtc_b, dtw_b, dtb, dt_f, nullptr, BL, DIN, RR, 1);

  // 9) chunked selective scan (xz is dead now; hf/ap/carry alias it)
  scan_phase1<<<dim3(8192), 256, 0, stream>>>(dt_f, u_f, dbc, alog, hf_s, ap_s);
  scan_carry<<<dim3(512), 256, 0, stream>>>(hf_s, ap_s, carry_s);
  scan_phase3<<<dim3(8192), 256, 0, stream>>>(dt_f, u_f, dbc, alog, dpar, gz_f, carry_s, ym_b);

  // 10) out_proj
  gemm_bt<<<dim3(8, 64), 256, 0, stream>>>(ym_b, opw_b, nullptr, mamba_o, nullptr, BL, DD, DIN, 0);

  // 11) residual + LayerNorm
  residual_ln<<<dim3(1024), 256, 0, stream>>>(x, attn_o, mamba_o, lnw, lnb, (float*)d_out);
}

// Round 4
// 664.914 us; speedup vs baseline: 2.4038x; 1.0390x over previous
//
#include <hip/hip_runtime.h>

typedef __attribute__((ext_vector_type(4))) float f32x4;
typedef __attribute__((ext_vector_type(8))) short short8;

#define DEV static __device__ __forceinline__

DEV ushort f2b(float f) {
  union { float f; unsigned u; } v; v.f = f;
  unsigned r = v.u + 0x7FFF + ((v.u >> 16) & 1);
  return (ushort)(r >> 16);
}

// DPP helpers (quad_perm / row_ror) and ds_swizzle xor
#define QP(x, ctrl) __int_as_float(__builtin_amdgcn_update_dpp(0, __float_as_int(x), (ctrl), 0xf, 0xf, false))
#define SWZ(x, off) __int_as_float(__builtin_amdgcn_ds_swizzle(__float_as_int(x), (off)))

// ---------------------------------------------------------------- constants
#define BB    2
#define LL    2048
#define DD    512
#define HH    8
#define EE    64
#define DIN   1024
#define NS    64
#define RR    32
#define BL    4096            // B*L
#define NCH   16              // scan chunks
#define TC    128             // steps per chunk (LL/NCH)
#define MFMA(a,b,c) __builtin_amdgcn_mfma_f32_16x16x32_bf16((a),(b),(c),0,0,0)

// ---------------------------------------------------------------- f32 -> bf16 multi-convert
struct CvtJobs {
  const float* src[9];
  ushort*      dst[9];
  int          n[9];
};

__global__ __launch_bounds__(256) void cvt_multi(CvtJobs j) {
  int job = blockIdx.y;
  const float* s = j.src[job];
  ushort* d = j.dst[job];
  int n = j.n[job];
  for (int i = blockIdx.x * 256 + threadIdx.x; i < n; i += gridDim.x * 256)
    d[i] = f2b(s[i]);
}

// ---------------------------------------------------------------- generic GEMM: C = A @ W^T (+bias)(+softplus)
__global__ __launch_bounds__(256) void gemm_bt(
    const ushort* __restrict__ A, const ushort* __restrict__ W,
    const float* __restrict__ bias, float* __restrict__ outF,
    ushort* __restrict__ outB, int M, int N, int K, int act)
{
  __shared__ ushort As[64][40];
  __shared__ ushort Ws[64][40];
  int m0 = blockIdx.y * 64, n0 = blockIdx.x * 64;
  int tid = threadIdx.x, l = tid & 63, w = tid >> 6;
  int wm = (w >> 1) * 32, wn = (w & 1) * 32;
  int lr = l & 15, kl = (l >> 4) * 8;
  int srow = tid >> 2, sk = (tid & 3) * 8;
  f32x4 acc[2][2] = {};

  for (int k0 = 0; k0 < K; k0 += 32) {
    uint4 av = *(const uint4*)&A[(size_t)(m0 + srow) * K + k0 + sk];
    uint4 wv;
    if (n0 + srow < N) wv = *(const uint4*)&W[(size_t)(n0 + srow) * K + k0 + sk];
    else { wv.x = 0; wv.y = 0; wv.z = 0; wv.w = 0; }
    *(uint4*)&As[srow][sk] = av;
    *(uint4*)&Ws[srow][sk] = wv;
    __syncthreads();
    short8 a0 = *(const short8*)&As[wm + lr][kl];
    short8 a1 = *(const short8*)&As[wm + 16 + lr][kl];
    short8 b0 = *(const short8*)&Ws[wn + lr][kl];
    short8 b1 = *(const short8*)&Ws[wn + 16 + lr][kl];
    acc[0][0] = MFMA(a0, b0, acc[0][0]);
    acc[0][1] = MFMA(a0, b1, acc[0][1]);
    acc[1][0] = MFMA(a1, b0, acc[1][0]);
    acc[1][1] = MFMA(a1, b1, acc[1][1]);
    __syncthreads();
  }

  #pragma unroll
  for (int mi = 0; mi < 2; mi++)
    #pragma unroll
    for (int ni = 0; ni < 2; ni++) {
      int rbase = m0 + wm + mi * 16 + ((l >> 4) << 2);
      int col = n0 + wn + ni * 16 + lr;
      if (col < N) {
        float bval = bias ? bias[col] : 0.f;
        #pragma unroll
        for (int r = 0; r < 4; r++) {
          float v = acc[mi][ni][r] + bval;
          if (act == 1) v = (v > 20.f) ? v : log1pf(__expf(v));
          size_t o = (size_t)(rbase + r) * N + col;
          if (outF) outF[o] = v;
          if (outB) outB[o] = f2b(v);
        }
      }
    }
}

// ---------------------------------------------------------------- flash attention (causal, e=64)
__global__ __launch_bounds__(256) void flash_attn(
    const ushort* __restrict__ qb, const ushort* __restrict__ kb,
    const ushort* __restrict__ vb, ushort* __restrict__ ctx)
{
  __shared__ ushort Qs[64][72];
  __shared__ ushort Ks[64][72];
  __shared__ ushort Vt[64][72];
  __shared__ ushort Ps[64][72];

  int qt = blockIdx.x, h = blockIdx.y, b = blockIdx.z;
  int tid = threadIdx.x, l = tid & 63, w = tid >> 6;
  int w16 = w * 16, lr = l & 15, kl = (l >> 4) * 8;

  for (int i = tid; i < 512; i += 256) {
    int row = i >> 3, c8 = (i & 7) * 8;
    *(uint4*)&Qs[row][c8] =
        *(const uint4*)&qb[((size_t)(b * LL + qt * 64 + row)) * DD + h * EE + c8];
  }
  __syncthreads();

  float m_r[4] = {-1e30f, -1e30f, -1e30f, -1e30f};
  float l_r[4] = {0.f, 0.f, 0.f, 0.f};
  f32x4 oacc[4] = {};

  for (int kv = 0; kv <= qt; kv++) {
    for (int i = tid; i < 512; i += 256) {
      int s = i >> 3, c8 = (i & 7) * 8;
      *(uint4*)&Ks[s][c8] =
          *(const uint4*)&kb[((size_t)(b * LL + kv * 64 + s)) * DD + h * EE + c8];
      uint4 vv = *(const uint4*)&vb[((size_t)(b * LL + kv * 64 + s)) * DD + h * EE + c8];
      const ushort* pv = (const ushort*)&vv;
      #pragma unroll
      for (int jj = 0; jj < 8; jj++) Vt[c8 + jj][s] = pv[jj];
    }
    __syncthreads();

    f32x4 sacc[4] = {};
    #pragma unroll
    for (int kk = 0; kk < 2; kk++) {
      short8 aq = *(const short8*)&Qs[w16 + lr][kk * 32 + kl];
      #pragma unroll
      for (int nt = 0; nt < 4; nt++) {
        short8 bk8 = *(const short8*)&Ks[nt * 16 + lr][kk * 32 + kl];
        sacc[nt] = MFMA(aq, bk8, sacc[nt]);
      }
    }

    bool diag = (kv == qt);
    float scl[4];
    #pragma unroll
    for (int r = 0; r < 4; r++) {
      int rloc = w16 + ((l >> 4) << 2) + r;
      float sv[4];
      #pragma unroll
      for (int nt = 0; nt < 4; nt++) {
        float v = sacc[nt][r] * 0.125f;
        if (diag && (nt * 16 + lr) > rloc) v = -1e30f;
        sv[nt] = v;
      }
      float mx = fmaxf(fmaxf(sv[0], sv[1]), fmaxf(sv[2], sv[3]));
      #pragma unroll
      for (int o = 1; o < 16; o <<= 1) mx = fmaxf(mx, __shfl_xor(mx, o));
      float mnew = fmaxf(m_r[r], mx);
      float sc = __expf(m_r[r] - mnew);
      float rs = 0.f;
      #pragma unroll
      for (int nt = 0; nt < 4; nt++) {
        float p = __expf(sv[nt] - mnew);
        rs += p;
        Ps[rloc][nt * 16 + lr] = f2b(p);
      }
      #pragma unroll
      for (int o = 1; o < 16; o <<= 1) rs += __shfl_xor(rs, o);
      l_r[r] = l_r[r] * sc + rs;
      m_r[r] = mnew;
      scl[r] = sc;
    }
    #pragma unroll
    for (int nt = 0; nt < 4; nt++)
      #pragma unroll
      for (int r = 0; r < 4; r++) oacc[nt][r] *= scl[r];

    #pragma unroll
    for (int kk = 0; kk < 2; kk++) {
      short8 ap = *(const short8*)&Ps[w16 + lr][kk * 32 + kl];
      #pragma unroll
      for (int nt = 0; nt < 4; nt++) {
        short8 bv8 = *(const short8*)&Vt[nt * 16 + lr][kk * 32 + kl];
        oacc[nt] = MFMA(ap, bv8, oacc[nt]);
      }
    }
    __syncthreads();
  }

  #pragma unroll
  for (int nt = 0; nt < 4; nt++)
    #pragma unroll
    for (int r = 0; r < 4; r++) {
      int row = qt * 64 + w16 + ((l >> 4) << 2) + r;
      float v = oacc[nt][r] / l_r[r];
      ctx[((size_t)(b * LL + row)) * DD + h * EE + nt * 16 + lr] = f2b(v);
    }
}

// ---------------------------------------------------------------- depthwise causal conv (K=4) + SiLU
__global__ __launch_bounds__(256) void conv_silu(
    const float* __restrict__ xz, const float* __restrict__ cw,
    const float* __restrict__ cb, float* __restrict__ u, ushort* __restrict__ ub)
{
  int i = blockIdx.x * 256 + threadIdx.x;
  if (i >= BL * DIN) return;
  int d = i & (DIN - 1);
  int bl = i >> 10;
  int t = bl & (LL - 1);
  int b = bl >> 11;
  float s = cb[d];
  #pragma unroll
  for (int j = 0; j < 4; j++) {
    int tt = t - 3 + j;
    if (tt >= 0) s += xz[((size_t)(b * LL + tt)) * (2 * DIN) + d] * cw[d * 4 + j];
  }
  float r = s / (1.f + __expf(-s));
  u[i] = r;
  ub[i] = f2b(r);
}

// ---------------------------------------------------------------- slice dbc[:, :32] -> bf16
__global__ __launch_bounds__(256) void slice_dt(
    const float* __restrict__ dbc, ushort* __restrict__ dtc)
{
  int i = blockIdx.x * 256 + threadIdx.x;
  if (i >= BL * RR) return;
  int m = i >> 5, r = i & 31;
  dtc[i] = f2b(dbc[m * 160 + r]);
}

// ---------------------------------------------------------------- pack B,C: bcp[b][t/2][n] = {B_t, C_t, B_t1, C_t1}
__global__ __launch_bounds__(256) void pack_bc(
    const float* __restrict__ dbc, float* __restrict__ bcp)
{
  int i = blockIdx.x * 256 + threadIdx.x;     // BB*1024*64
  if (i >= BB * (LL / 2) * NS) return;
  int n = i & 63, tp = (i >> 6) & 1023, b = i >> 16;
  size_t r0 = ((size_t)(b * LL + 2 * tp)) * 160;
  float4 v;
  v.x = dbc[r0 + 32 + n];
  v.y = dbc[r0 + 96 + n];
  v.z = dbc[r0 + 160 + 32 + n];
  v.w = dbc[r0 + 160 + 96 + n];
  *(float4*)&bcp[(size_t)i * 4] = v;
}

// ---------------------------------------------------------------- chunked scan, phase 1
// wave per (b, c, d); lane = n. dt/dtu preloaded in LDS; A-product via sum(dt).
__global__ __launch_bounds__(256) void scan_phase1(
    const float* __restrict__ dtf, const float* __restrict__ uf,
    const float* __restrict__ bcp, const float* __restrict__ alog,
    float* __restrict__ hf, float* __restrict__ ap)
{
  __shared__ float lds[4][TC][2];
  int tid = threadIdx.x, w = tid >> 6, l = tid & 63;
  int wid = blockIdx.x * 4 + w;
  int d = wid & (DIN - 1);
  int c = (wid >> 10) & (NCH - 1);
  int b = wid >> 14;
  float An2 = -__expf(alog[d * NS + l]) * 1.44269504f;

  size_t rowb = (size_t)(b * LL + c * TC);
  float Sd = 0.f;
  #pragma unroll
  for (int q = 0; q < 2; q++) {
    int t = q * 64 + l;
    float dtv = dtf[(rowb + t) * DIN + d];
    float uv  = uf [(rowb + t) * DIN + d];
    lds[w][t][0] = dtv;
    lds[w][t][1] = dtv * uv;
    Sd += dtv;
  }
  #pragma unroll
  for (int o = 1; o < 64; o <<= 1) Sd += __shfl_xor(Sd, o);
  __syncthreads();

  const float4* bq = (const float4*)bcp + ((size_t)(b * 1024 + c * 64) * 64 + l);
  float h = 0.f;
  for (int g = 0; g < 16; g++) {
    float4 bcs[4];
    bcs[0] = bq[0]; bcs[1] = bq[64]; bcs[2] = bq[128]; bcs[3] = bq[192];
    const float* gb = &lds[w][g * 8][0];
    #pragma unroll
    for (int j = 0; j < 8; j++) {
      float2 dd = *(const float2*)(gb + j * 2);
      float Bv = (j & 1) ? bcs[j >> 1].z : bcs[j >> 1].x;
      float a = exp2f(dd.x * An2);
      h = a * h + dd.y * Bv;
    }
    bq += 256;
  }
  size_t o = (((size_t)((b << 10) + d) * NCH) + c) * 64 + l;
  hf[o] = h;
  ap[o] = exp2f(Sd * An2);
}

// ---------------------------------------------------------------- chunked scan, phase 2 (carry combine)
__global__ __launch_bounds__(256) void scan_carry(
    const float* __restrict__ hf, const float* __restrict__ ap,
    float* __restrict__ carry)
{
  int i = blockIdx.x * 256 + threadIdx.x;   // (b, d, n)
  int n = i & 63;
  int d = (i >> 6) & (DIN - 1);
  int b = i >> 16;
  size_t base = ((size_t)((b << 10) + d) * NCH) * 64 + n;
  float cur = 0.f;
  #pragma unroll
  for (int c = 0; c < NCH; c++) {
    carry[base + (size_t)c * 64] = cur;
    cur = ap[base + (size_t)c * 64] * cur + hf[base + (size_t)c * 64];
  }
}

// ---------------------------------------------------------------- chunked scan, phase 3
// batched-8 deferred reduce; epilogue (D skip + gate) folded via LDS pairs.
__global__ __launch_bounds__(256) void scan_phase3(
    const float* __restrict__ dtf, const float* __restrict__ uf,
    const float* __restrict__ xz, const float* __restrict__ bcp,
    const float* __restrict__ alog, const float* __restrict__ dpar,
    const float* __restrict__ carry, ushort* __restrict__ ymb)
{
  __shared__ float lds[4][TC][4];
  int tid = threadIdx.x, w = tid >> 6, l = tid & 63;
  int wid = blockIdx.x * 4 + w;
  int d = wid & (DIN - 1);
  int c = (wid >> 10) & (NCH - 1);
  int b = wid >> 14;
  float An2 = -__expf(alog[d * NS + l]) * 1.44269504f;
  float Dv = dpar[d];

  size_t rowb = (size_t)(b * LL + c * TC);
  #pragma unroll
  for (int q = 0; q < 2; q++) {
    int t = q * 64 + l;
    float dtv = dtf[(rowb + t) * DIN + d];
    float uv  = uf [(rowb + t) * DIN + d];
    float zz  = xz [(rowb + t) * (2 * DIN) + DIN + d];
    float gzv = zz / (1.f + __expf(-zz));
    lds[w][t][0] = dtv;
    lds[w][t][1] = dtv * uv;
    lds[w][t][2] = gzv;
    lds[w][t][3] = uv * Dv * gzv;
  }
  __syncthreads();

  float h = carry[(((size_t)((b << 10) + d) * NCH) + c) * 64 + l];
  const float4* bq = (const float4*)bcp + ((size_t)(b * 1024 + c * 64) * 64 + l);
  ushort* ym0 = ymb + rowb * DIN + d;
  bool s1 = l & 1, s2 = l & 2, s4 = l & 4;
  bool wl = l < 8;

  for (int g = 0; g < 16; g++) {
    float4 bcs[4];
    bcs[0] = bq[0]; bcs[1] = bq[64]; bcs[2] = bq[128]; bcs[3] = bq[192];
    const float* gb = &lds[w][g * 8][0];
    float p[8];
    #pragma unroll
    for (int j = 0; j < 8; j++) {
      float2 dd = *(const float2*)(gb + j * 4);
      float Bv = (j & 1) ? bcs[j >> 1].z : bcs[j >> 1].x;
      float Cv = (j & 1) ? bcs[j >> 1].w : bcs[j >> 1].y;
      float a = exp2f(dd.x * An2);
      h = a * h + dd.y * Bv;
      p[j] = h * Cv;
    }
    // batched 8-sum reduce over 64 lanes: lane l ends with S_{l&7}
    #pragma unroll
    for (int j = 0; j < 8; j++) p[j] += QP(p[j], 0xB1);       // xor1 (quad_perm)
    float q0 = s1 ? p[1] : p[0];
    float q1 = s1 ? p[3] : p[2];
    float q2 = s1 ? p[5] : p[4];
    float q3 = s1 ? p[7] : p[6];
    q0 += QP(q0, 0x4E); q1 += QP(q1, 0x4E);                   // xor2
    q2 += QP(q2, 0x4E); q3 += QP(q3, 0x4E);
    float r0 = s2 ? q1 : q0;
    float r1 = s2 ? q3 : q2;
    r0 += SWZ(r0, 0x101F); r1 += SWZ(r1, 0x101F);             // xor4
    float s = s4 ? r1 : r0;
    s += QP(s, 0x128);                                        // xor8 (row_ror:8)
    s += SWZ(s, 0x401F);                                      // xor16
    s += __shfl_xor(s, 32);                                   // xor32

    float2 sgv = *(const float2*)(&lds[w][g * 8 + (l & 7)][2]);
    float yt = s * sgv.x + sgv.y;
    if (wl) ym0[(g * 8 + l) * DIN] = f2b(yt);
    bq += 256;
  }
}

// ---------------------------------------------------------------- residual + LayerNorm
__global__ __launch_bounds__(256) void residual_ln(
    const float* __restrict__ x, const float* __restrict__ at,
    const float* __restrict__ mb, const float* __restrict__ lw,
    const float* __restrict__ lb, float* __restrict__ out)
{
  int row = blockIdx.x * 4 + (threadIdx.x >> 6);
  int l = threadIdx.x & 63;
  size_t base = (size_t)row * DD;
  float h[8];
  float s = 0.f, s2 = 0.f;
  #pragma unroll
  for (int half = 0; half < 2; half++) {
    int c = half * 256 + l * 4;
    float4 xv = *(const float4*)(x + base + c);
    float4 av = *(const float4*)(at + base + c);
    float4 mv = *(const float4*)(mb + base + c);
    float* hp = h + half * 4;
    hp[0] = xv.x + av.x + mv.x;
    hp[1] = xv.y + av.y + mv.y;
    hp[2] = xv.z + av.z + mv.z;
    hp[3] = xv.w + av.w + mv.w;
    #pragma unroll
    for (int j = 0; j < 4; j++) { s += hp[j]; s2 += hp[j] * hp[j]; }
  }
  #pragma unroll
  for (int o = 1; o < 64; o <<= 1) { s += __shfl_xor(s, o); s2 += __shfl_xor(s2, o); }
  float mean = s * (1.f / DD);
  float var = s2 * (1.f / DD) - mean * mean;
  float rs = rsqrtf(var + 1e-5f);
  #pragma unroll
  for (int half = 0; half < 2; half++) {
    int c = half * 256 + l * 4;
    float4 ov;
    ov.x = (h[half*4+0] - mean) * rs * lw[c+0] + lb[c+0];
    ov.y = (h[half*4+1] - mean) * rs * lw[c+1] + lb[c+1];
    ov.z = (h[half*4+2] - mean) * rs * lw[c+2] + lb[c+2];
    ov.w = (h[half*4+3] - mean) * rs * lw[c+3] + lb[c+3];
    *(float4*)(out + base + c) = ov;
  }
}

// ---------------------------------------------------------------- host
extern "C" void kernel_launch(void* const* d_in, const int* in_sizes, int n_in,
                              void* d_out, int out_size, void* d_ws, size_t ws_size,
                              hipStream_t stream) {
  const float* x    = (const float*)d_in[0];
  const float* wq   = (const float*)d_in[1];
  const float* bq   = (const float*)d_in[2];
  const float* wk   = (const float*)d_in[3];
  const float* bk   = (const float*)d_in[4];
  const float* wv   = (const float*)d_in[5];
  const float* bv   = (const float*)d_in[6];
  const float* wo   = (const float*)d_in[7];
  const float* bo   = (const float*)d_in[8];
  const float* inw  = (const float*)d_in[9];
  const float* cw   = (const float*)d_in[10];
  const float* cb   = (const float*)d_in[11];
  const float* xpw  = (const float*)d_in[12];
  const float* dtw  = (const float*)d_in[13];
  const float* dtb  = (const float*)d_in[14];
  const float* alog = (const float*)d_in[15];
  const float* dpar = (const float*)d_in[16];
  const float* opw  = (const float*)d_in[17];
  const float* lnw  = (const float*)d_in[18];
  const float* lnb  = (const float*)d_in[19];

  char* ws = (char*)d_ws;
  size_t off = 0;
  auto alloc = [&](size_t bytes) -> void* {
    void* p = ws + off;
    off += (bytes + 255) & ~(size_t)255;
    return p;
  };

  const size_t BLD = (size_t)BL * DD;
  const size_t BLDIN = (size_t)BL * DIN;

  ushort* xf_b   = (ushort*)alloc(BLD * 2);
  ushort* wq_b   = (ushort*)alloc(DD * DD * 2);
  ushort* wk_b   = (ushort*)alloc(DD * DD * 2);
  ushort* wv_b   = (ushort*)alloc(DD * DD * 2);
  ushort* wo_b   = (ushort*)alloc(DD * DD * 2);
  ushort* inw_b  = (ushort*)alloc(2 * DIN * DD * 2);
  ushort* xpw_b  = (ushort*)alloc(160 * DIN * 2);
  ushort* dtw_b  = (ushort*)alloc(DIN * RR * 2);
  ushort* opw_b  = (ushort*)alloc(DD * DIN * 2);
  ushort* q_b    = (ushort*)alloc(BLD * 2);
  ushort* k_b    = (ushort*)alloc(BLD * 2);
  ushort* v_b    = (ushort*)alloc(BLD * 2);
  ushort* ctx_b  = (ushort*)alloc(BLD * 2);
  float*  attn_o = (float*)alloc(BLD * 4);
  float*  xz     = (float*)alloc(BL * (size_t)(2 * DIN) * 4);
  float*  u_f    = (float*)alloc(BLDIN * 4);
  ushort* u_b    = (ushort*)alloc(BLDIN * 2);
  float*  dbc    = (float*)alloc((size_t)BL * 160 * 4);
  ushort* dtc_b  = (ushort*)alloc((size_t)BL * RR * 2);
  float*  dt_f   = (float*)alloc(BLDIN * 4);
  ushort* ym_b   = (ushort*)alloc(BLDIN * 2);
  float*  mamba_o= (float*)alloc(BLD * 4);
  float*  bcp    = (float*)alloc((size_t)BB * (LL / 2) * NS * 4 * 4);  // 2.1 MB
  const size_t SCN = (size_t)BB * DIN * NCH * 64;
  float*  hf_s   = (float*)alloc(SCN * 4);
  float*  ap_s   = (float*)alloc(SCN * 4);
  float*  carry_s= (float*)alloc(SCN * 4);

  // 1) convert inputs to bf16
  CvtJobs cj;
  cj.src[0] = x;    cj.dst[0] = xf_b;  cj.n[0] = (int)BLD;
  cj.src[1] = wq;   cj.dst[1] = wq_b;  cj.n[1] = DD * DD;
  cj.src[2] = wk;   cj.dst[2] = wk_b;  cj.n[2] = DD * DD;
  cj.src[3] = wv;   cj.dst[3] = wv_b;  cj.n[3] = DD * DD;
  cj.src[4] = wo;   cj.dst[4] = wo_b;  cj.n[4] = DD * DD;
  cj.src[5] = inw;  cj.dst[5] = inw_b; cj.n[5] = 2 * DIN * DD;
  cj.src[6] = xpw;  cj.dst[6] = xpw_b; cj.n[6] = 160 * DIN;
  cj.src[7] = dtw;  cj.dst[7] = dtw_b; cj.n[7] = DIN * RR;
  cj.src[8] = opw;  cj.dst[8] = opw_b; cj.n[8] = DD * DIN;
  cvt_multi<<<dim3(256, 9), 256, 0, stream>>>(cj);

  // 2) q,k,v projections
  gemm_bt<<<dim3(8, 64), 256, 0, stream>>>(xf_b, wq_b, bq, nullptr, q_b, BL, DD, DD, 0);
  gemm_bt<<<dim3(8, 64), 256, 0, stream>>>(xf_b, wk_b, bk, nullptr, k_b, BL, DD, DD, 0);
  gemm_bt<<<dim3(8, 64), 256, 0, stream>>>(xf_b, wv_b, bv, nullptr, v_b, BL, DD, DD, 0);

  // 3) flash attention
  flash_attn<<<dim3(32, HH, BB), 256, 0, stream>>>(q_b, k_b, v_b, ctx_b);

  // 4) output projection
  gemm_bt<<<dim3(8, 64), 256, 0, stream>>>(ctx_b, wo_b, bo, attn_o, nullptr, BL, DD, DD, 0);

  // 5) mamba in_proj
  gemm_bt<<<dim3(32, 64), 256, 0, stream>>>(xf_b, inw_b, nullptr, xz, nullptr, BL, 2 * DIN, DD, 0);

  // 6) depthwise conv + SiLU
  conv_silu<<<dim3(32768), 256, 0, stream>>>(xz, cw, cb, u_f, u_b);

  // 7) x_proj
  gemm_bt<<<dim3(3, 64), 256, 0, stream>>>(u_b, xpw_b, nullptr, dbc, nullptr, BL, 160, DIN, 0);

  // 8) dt slice + dt_proj + softplus
  slice_dt<<<dim3(512), 256, 0, stream>>>(dbc, dtc_b);
  gemm_bt<<<dim3(16, 64), 256, 0, stream>>>(dtc_b, dtw_b, dtb, dt_f, nullptr, BL, DIN, RR, 1);

  // 9) pack B/C, then chunked selective scan
  pack_bc<<<dim3(512), 256, 0, stream>>>(dbc, bcp);
  scan_phase1<<<dim3(8192), 256, 0, stream>>>(dt_f, u_f, bcp, alog, hf_s, ap_s);
  scan_carry<<<dim3(512), 256, 0, stream>>>(hf_s, ap_s, carry_s);
  scan_phase3<<<dim3(8192), 256, 0, stream>>>(dt_f, u_f, xz, bcp, alog, dpar, carry_s, ym_b);

  // 10) out_proj
  gemm_bt<<<dim3(8, 64), 256, 0, stream>>>(ym_b, opw_b, nullptr, mamba_o, nullptr, BL, DD, DIN, 0);

  // 11) residual + LayerNorm
  residual_ln<<<dim3(1024), 256, 0, stream>>>(x, attn_o, mamba_o, lnw, lnb, (float*)d_out);
}

// Round 5
// 635.911 us; speedup vs baseline: 2.5135x; 1.0456x over previous
//
#include <hip/hip_runtime.h>

typedef __attribute__((ext_vector_type(4))) float f32x4;
typedef __attribute__((ext_vector_type(8))) short short8;

#define DEV static __device__ __forceinline__

DEV ushort f2b(float f) {
  union { float f; unsigned u; } v; v.f = f;
  unsigned r = v.u + 0x7FFF + ((v.u >> 16) & 1);
  return (ushort)(r >> 16);
}
DEV unsigned pack_bf2(float lo, float hi) {
  return (unsigned)f2b(lo) | ((unsigned)f2b(hi) << 16);
}
DEV float bflo(unsigned p) { return __uint_as_float(p << 16); }
DEV float bfhi(unsigned p) { return __uint_as_float(p & 0xFFFF0000u); }

// DPP helpers (quad_perm / row_ror) and ds_swizzle xor
#define QP(x, ctrl) __int_as_float(__builtin_amdgcn_update_dpp(0, __float_as_int(x), (ctrl), 0xf, 0xf, false))
#define SWZ(x, off) __int_as_float(__builtin_amdgcn_ds_swizzle(__float_as_int(x), (off)))

// ---------------------------------------------------------------- constants
#define BB    2
#define LL    2048
#define DD    512
#define HH    8
#define EE    64
#define DIN   1024
#define NS    64
#define RR    32
#define BL    4096            // B*L
#define NCH   16              // scan chunks
#define TC    128             // steps per chunk (LL/NCH)
#define MFMA(a,b,c) __builtin_amdgcn_mfma_f32_16x16x32_bf16((a),(b),(c),0,0,0)

// ---------------------------------------------------------------- f32 -> bf16 multi-convert
struct CvtJobs {
  const float* src[9];
  ushort*      dst[9];
  int          n[9];
};

__global__ __launch_bounds__(256) void cvt_multi(CvtJobs j) {
  int job = blockIdx.y;
  const float* s = j.src[job];
  ushort* d = j.dst[job];
  int n = j.n[job];
  for (int i = blockIdx.x * 256 + threadIdx.x; i < n; i += gridDim.x * 256)
    d[i] = f2b(s[i]);
}

// ---------------------------------------------------------------- generic GEMM: C = A @ W^T (+bias)(+softplus)
__global__ __launch_bounds__(256) void gemm_bt(
    const ushort* __restrict__ A, const ushort* __restrict__ W,
    const float* __restrict__ bias, float* __restrict__ outF,
    ushort* __restrict__ outB, int M, int N, int K, int act)
{
  __shared__ ushort As[64][40];
  __shared__ ushort Ws[64][40];
  int m0 = blockIdx.y * 64, n0 = blockIdx.x * 64;
  int tid = threadIdx.x, l = tid & 63, w = tid >> 6;
  int wm = (w >> 1) * 32, wn = (w & 1) * 32;
  int lr = l & 15, kl = (l >> 4) * 8;
  int srow = tid >> 2, sk = (tid & 3) * 8;
  f32x4 acc[2][2] = {};

  for (int k0 = 0; k0 < K; k0 += 32) {
    uint4 av = *(const uint4*)&A[(size_t)(m0 + srow) * K + k0 + sk];
    uint4 wv;
    if (n0 + srow < N) wv = *(const uint4*)&W[(size_t)(n0 + srow) * K + k0 + sk];
    else { wv.x = 0; wv.y = 0; wv.z = 0; wv.w = 0; }
    *(uint4*)&As[srow][sk] = av;
    *(uint4*)&Ws[srow][sk] = wv;
    __syncthreads();
    short8 a0 = *(const short8*)&As[wm + lr][kl];
    short8 a1 = *(const short8*)&As[wm + 16 + lr][kl];
    short8 b0 = *(const short8*)&Ws[wn + lr][kl];
    short8 b1 = *(const short8*)&Ws[wn + 16 + lr][kl];
    acc[0][0] = MFMA(a0, b0, acc[0][0]);
    acc[0][1] = MFMA(a0, b1, acc[0][1]);
    acc[1][0] = MFMA(a1, b0, acc[1][0]);
    acc[1][1] = MFMA(a1, b1, acc[1][1]);
    __syncthreads();
  }

  #pragma unroll
  for (int mi = 0; mi < 2; mi++)
    #pragma unroll
    for (int ni = 0; ni < 2; ni++) {
      int rbase = m0 + wm + mi * 16 + ((l >> 4) << 2);
      int col = n0 + wn + ni * 16 + lr;
      if (col < N) {
        float bval = bias ? bias[col] : 0.f;
        #pragma unroll
        for (int r = 0; r < 4; r++) {
          float v = acc[mi][ni][r] + bval;
          if (act == 1) v = (v > 20.f) ? v : log1pf(__expf(v));
          size_t o = (size_t)(rbase + r) * N + col;
          if (outF) outF[o] = v;
          if (outB) outB[o] = f2b(v);
        }
      }
    }
}

// ---------------------------------------------------------------- flash attention (causal, e=64)
__global__ __launch_bounds__(256) void flash_attn(
    const ushort* __restrict__ qb, const ushort* __restrict__ kb,
    const ushort* __restrict__ vb, ushort* __restrict__ ctx)
{
  __shared__ ushort Qs[64][72];
  __shared__ ushort Ks[64][72];
  __shared__ ushort Vt[64][72];
  __shared__ ushort Ps[64][72];

  int qt = blockIdx.x, h = blockIdx.y, b = blockIdx.z;
  int tid = threadIdx.x, l = tid & 63, w = tid >> 6;
  int w16 = w * 16, lr = l & 15, kl = (l >> 4) * 8;

  for (int i = tid; i < 512; i += 256) {
    int row = i >> 3, c8 = (i & 7) * 8;
    *(uint4*)&Qs[row][c8] =
        *(const uint4*)&qb[((size_t)(b * LL + qt * 64 + row)) * DD + h * EE + c8];
  }
  __syncthreads();

  float m_r[4] = {-1e30f, -1e30f, -1e30f, -1e30f};
  float l_r[4] = {0.f, 0.f, 0.f, 0.f};
  f32x4 oacc[4] = {};

  for (int kv = 0; kv <= qt; kv++) {
    for (int i = tid; i < 512; i += 256) {
      int s = i >> 3, c8 = (i & 7) * 8;
      *(uint4*)&Ks[s][c8] =
          *(const uint4*)&kb[((size_t)(b * LL + kv * 64 + s)) * DD + h * EE + c8];
      uint4 vv = *(const uint4*)&vb[((size_t)(b * LL + kv * 64 + s)) * DD + h * EE + c8];
      const ushort* pv = (const ushort*)&vv;
      #pragma unroll
      for (int jj = 0; jj < 8; jj++) Vt[c8 + jj][s] = pv[jj];
    }
    __syncthreads();

    f32x4 sacc[4] = {};
    #pragma unroll
    for (int kk = 0; kk < 2; kk++) {
      short8 aq = *(const short8*)&Qs[w16 + lr][kk * 32 + kl];
      #pragma unroll
      for (int nt = 0; nt < 4; nt++) {
        short8 bk8 = *(const short8*)&Ks[nt * 16 + lr][kk * 32 + kl];
        sacc[nt] = MFMA(aq, bk8, sacc[nt]);
      }
    }

    bool diag = (kv == qt);
    float scl[4];
    #pragma unroll
    for (int r = 0; r < 4; r++) {
      int rloc = w16 + ((l >> 4) << 2) + r;
      float sv[4];
      #pragma unroll
      for (int nt = 0; nt < 4; nt++) {
        float v = sacc[nt][r] * 0.125f;
        if (diag && (nt * 16 + lr) > rloc) v = -1e30f;
        sv[nt] = v;
      }
      float mx = fmaxf(fmaxf(sv[0], sv[1]), fmaxf(sv[2], sv[3]));
      #pragma unroll
      for (int o = 1; o < 16; o <<= 1) mx = fmaxf(mx, __shfl_xor(mx, o));
      float mnew = fmaxf(m_r[r], mx);
      float sc = __expf(m_r[r] - mnew);
      float rs = 0.f;
      #pragma unroll
      for (int nt = 0; nt < 4; nt++) {
        float p = __expf(sv[nt] - mnew);
        rs += p;
        Ps[rloc][nt * 16 + lr] = f2b(p);
      }
      #pragma unroll
      for (int o = 1; o < 16; o <<= 1) rs += __shfl_xor(rs, o);
      l_r[r] = l_r[r] * sc + rs;
      m_r[r] = mnew;
      scl[r] = sc;
    }
    #pragma unroll
    for (int nt = 0; nt < 4; nt++)
      #pragma unroll
      for (int r = 0; r < 4; r++) oacc[nt][r] *= scl[r];

    #pragma unroll
    for (int kk = 0; kk < 2; kk++) {
      short8 ap = *(const short8*)&Ps[w16 + lr][kk * 32 + kl];
      #pragma unroll
      for (int nt = 0; nt < 4; nt++) {
        short8 bv8 = *(const short8*)&Vt[nt * 16 + lr][kk * 32 + kl];
        oacc[nt] = MFMA(ap, bv8, oacc[nt]);
      }
    }
    __syncthreads();
  }

  #pragma unroll
  for (int nt = 0; nt < 4; nt++)
    #pragma unroll
    for (int r = 0; r < 4; r++) {
      int row = qt * 64 + w16 + ((l >> 4) << 2) + r;
      float v = oacc[nt][r] / l_r[r];
      ctx[((size_t)(b * LL + row)) * DD + h * EE + nt * 16 + lr] = f2b(v);
    }
}

// ---------------------------------------------------------------- depthwise causal conv (K=4) + SiLU
__global__ __launch_bounds__(256) void conv_silu(
    const float* __restrict__ xz, const float* __restrict__ cw,
    const float* __restrict__ cb, float* __restrict__ u, ushort* __restrict__ ub)
{
  int i = blockIdx.x * 256 + threadIdx.x;
  if (i >= BL * DIN) return;
  int d = i & (DIN - 1);
  int bl = i >> 10;
  int t = bl & (LL - 1);
  int b = bl >> 11;
  float s = cb[d];
  #pragma unroll
  for (int j = 0; j < 4; j++) {
    int tt = t - 3 + j;
    if (tt >= 0) s += xz[((size_t)(b * LL + tt)) * (2 * DIN) + d] * cw[d * 4 + j];
  }
  float r = s / (1.f + __expf(-s));
  u[i] = r;
  ub[i] = f2b(r);
}

// ---------------------------------------------------------------- slice dbc[:, :32] -> bf16
__global__ __launch_bounds__(256) void slice_dt(
    const float* __restrict__ dbc, ushort* __restrict__ dtc)
{
  int i = blockIdx.x * 256 + threadIdx.x;
  if (i >= BL * RR) return;
  int m = i >> 5, r = i & 31;
  dtc[i] = f2b(dbc[m * 160 + r]);
}

// ---------------------------------------------------------------- pack B,C: bcp[b][t/2][n] = {B_t, C_t, B_t1, C_t1}
__global__ __launch_bounds__(256) void pack_bc(
    const float* __restrict__ dbc, float* __restrict__ bcp)
{
  int i = blockIdx.x * 256 + threadIdx.x;     // BB*1024*64
  if (i >= BB * (LL / 2) * NS) return;
  int n = i & 63, tp = (i >> 6) & 1023, b = i >> 16;
  size_t r0 = ((size_t)(b * LL + 2 * tp)) * 160;
  float4 v;
  v.x = dbc[r0 + 32 + n];
  v.y = dbc[r0 + 96 + n];
  v.z = dbc[r0 + 160 + 32 + n];
  v.w = dbc[r0 + 160 + 96 + n];
  *(float4*)&bcp[(size_t)i * 4] = v;
}

// ---------------------------------------------------------------- pack dt/u/z: time-major bf16x2 arrays
// dtu_p[(b*DIN+d)*LL+t] = {dt, dt*u};  sg_p[...] = {gz, u*D*gz}
__global__ __launch_bounds__(256) void pack_dtu(
    const float* __restrict__ dtf, const float* __restrict__ uf,
    const float* __restrict__ xz, const float* __restrict__ dpar,
    unsigned* __restrict__ dtu_p, unsigned* __restrict__ sg_p)
{
  __shared__ float s_dt[32][65], s_du[32][65], s_gz[32][65], s_ug[32][65];
  int d0 = blockIdx.x * 64, t0 = blockIdx.y * 32;
  int tid = threadIdx.x;
  int c = tid & 63, r4 = tid >> 6;
  float Dv = dpar[d0 + c];
  #pragma unroll
  for (int k = 0; k < 8; k++) {
    int r = k * 4 + r4;
    size_t row = (size_t)(t0 + r);
    float dtv = dtf[row * DIN + d0 + c];
    float uv  = uf [row * DIN + d0 + c];
    float zz  = xz [row * (2 * DIN) + DIN + d0 + c];
    float g = zz / (1.f + __expf(-zz));
    s_dt[r][c] = dtv;
    s_du[r][c] = dtv * uv;
    s_gz[r][c] = g;
    s_ug[r][c] = uv * Dv * g;
  }
  __syncthreads();
  int dl = tid >> 2, q = tid & 3;
  int b = t0 >> 11, tl0 = t0 & (LL - 1);
  size_t obase = ((size_t)(b * DIN + d0 + dl)) * LL + tl0 + q * 8;
  #pragma unroll
  for (int tt = 0; tt < 8; tt++) {
    int t = q * 8 + tt;
    dtu_p[obase + tt] = pack_bf2(s_dt[t][dl], s_du[t][dl]);
    sg_p [obase + tt] = pack_bf2(s_gz[t][dl], s_ug[t][dl]);
  }
}

// ---------------------------------------------------------------- chunked scan, phase 1
// wave per (b, c, d); lane = n. dt/dtu preloaded coalesced into LDS.
__global__ __launch_bounds__(256) void scan_phase1(
    const unsigned* __restrict__ dtu_p, const float* __restrict__ bcp,
    const float* __restrict__ alog, float* __restrict__ hf, float* __restrict__ ap)
{
  __shared__ float lds[4][TC][2];
  int tid = threadIdx.x, w = tid >> 6, l = tid & 63;
  int wid = blockIdx.x * 4 + w;
  int d = wid & (DIN - 1);
  int c = (wid >> 10) & (NCH - 1);
  int b = wid >> 14;
  float An2 = -__expf(alog[d * NS + l]) * 1.44269504f;

  size_t pbase = ((size_t)(b * DIN + d)) * LL + c * TC;
  float Sd = 0.f;
  #pragma unroll
  for (int q = 0; q < 2; q++) {
    unsigned pd = dtu_p[pbase + q * 64 + l];
    float dtv = bflo(pd);
    lds[w][q * 64 + l][0] = dtv;
    lds[w][q * 64 + l][1] = bfhi(pd);
    Sd += dtv;
  }
  #pragma unroll
  for (int o = 1; o < 64; o <<= 1) Sd += __shfl_xor(Sd, o);
  __syncthreads();

  const float4* bq = (const float4*)bcp + ((size_t)(b * 1024 + c * 64) * 64 + l);
  float h = 0.f;
  for (int g = 0; g < 16; g++) {
    float4 bcs[4];
    bcs[0] = bq[0]; bcs[1] = bq[64]; bcs[2] = bq[128]; bcs[3] = bq[192];
    const float* gb = &lds[w][g * 8][0];
    #pragma unroll
    for (int j = 0; j < 8; j++) {
      float2 dd = *(const float2*)(gb + j * 2);
      float Bv = (j & 1) ? bcs[j >> 1].z : bcs[j >> 1].x;
      float a = exp2f(dd.x * An2);
      h = a * h + dd.y * Bv;
    }
    bq += 256;
  }
  size_t o = (((size_t)((b << 10) + d) * NCH) + c) * 64 + l;
  hf[o] = h;
  ap[o] = exp2f(Sd * An2);
}

// ---------------------------------------------------------------- chunked scan, phase 2 (carry combine)
__global__ __launch_bounds__(256) void scan_carry(
    const float* __restrict__ hf, const float* __restrict__ ap,
    float* __restrict__ carry)
{
  int i = blockIdx.x * 256 + threadIdx.x;   // (b, d, n)
  int n = i & 63;
  int d = (i >> 6) & (DIN - 1);
  int b = i >> 16;
  size_t base = ((size_t)((b << 10) + d) * NCH) * 64 + n;
  float cur = 0.f;
  #pragma unroll
  for (int c = 0; c < NCH; c++) {
    carry[base + (size_t)c * 64] = cur;
    cur = ap[base + (size_t)c * 64] * cur + hf[base + (size_t)c * 64];
  }
}

// ---------------------------------------------------------------- chunked scan, phase 3
// batched-8 deferred reduce; epilogue via packed {gz, u*D*gz}.
__global__ __launch_bounds__(256) void scan_phase3(
    const unsigned* __restrict__ dtu_p, const unsigned* __restrict__ sg_p,
    const float* __restrict__ bcp, const float* __restrict__ alog,
    const float* __restrict__ carry, ushort* __restrict__ ymb)
{
  __shared__ float lds[4][TC][4];
  int tid = threadIdx.x, w = tid >> 6, l = tid & 63;
  int wid = blockIdx.x * 4 + w;
  int d = wid & (DIN - 1);
  int c = (wid >> 10) & (NCH - 1);
  int b = wid >> 14;
  float An2 = -__expf(alog[d * NS + l]) * 1.44269504f;

  size_t pbase = ((size_t)(b * DIN + d)) * LL + c * TC;
  #pragma unroll
  for (int q = 0; q < 2; q++) {
    unsigned pd = dtu_p[pbase + q * 64 + l];
    unsigned pg = sg_p [pbase + q * 64 + l];
    lds[w][q * 64 + l][0] = bflo(pd);
    lds[w][q * 64 + l][1] = bfhi(pd);
    lds[w][q * 64 + l][2] = bflo(pg);
    lds[w][q * 64 + l][3] = bfhi(pg);
  }
  __syncthreads();

  size_t rowb = (size_t)(b * LL + c * TC);
  float h = carry[(((size_t)((b << 10) + d) * NCH) + c) * 64 + l];
  const float4* bq = (const float4*)bcp + ((size_t)(b * 1024 + c * 64) * 64 + l);
  ushort* ym0 = ymb + rowb * DIN + d;
  bool s1 = l & 1, s2 = l & 2, s4 = l & 4;
  bool wl = l < 8;

  for (int g = 0; g < 16; g++) {
    float4 bcs[4];
    bcs[0] = bq[0]; bcs[1] = bq[64]; bcs[2] = bq[128]; bcs[3] = bq[192];
    const float* gb = &lds[w][g * 8][0];
    float p[8];
    #pragma unroll
    for (int j = 0; j < 8; j++) {
      float2 dd = *(const float2*)(gb + j * 4);
      float Bv = (j & 1) ? bcs[j >> 1].z : bcs[j >> 1].x;
      float Cv = (j & 1) ? bcs[j >> 1].w : bcs[j >> 1].y;
      float a = exp2f(dd.x * An2);
      h = a * h + dd.y * Bv;
      p[j] = h * Cv;
    }
    #pragma unroll
    for (int j = 0; j < 8; j++) p[j] += QP(p[j], 0xB1);       // xor1
    float q0 = s1 ? p[1] : p[0];
    float q1 = s1 ? p[3] : p[2];
    float q2 = s1 ? p[5] : p[4];
    float q3 = s1 ? p[7] : p[6];
    q0 += QP(q0, 0x4E); q1 += QP(q1, 0x4E);                   // xor2
    q2 += QP(q2, 0x4E); q3 += QP(q3, 0x4E);
    float r0 = s2 ? q1 : q0;
    float r1 = s2 ? q3 : q2;
    r0 += SWZ(r0, 0x101F); r1 += SWZ(r1, 0x101F);             // xor4
    float s = s4 ? r1 : r0;
    s += QP(s, 0x128);                                        // xor8 (row_ror:8)
    s += SWZ(s, 0x401F);                                      // xor16
    s += __shfl_xor(s, 32);                                   // xor32

    float2 sgv = *(const float2*)(&lds[w][g * 8 + (l & 7)][2]);
    float yt = s * sgv.x + sgv.y;
    if (wl) ym0[(g * 8 + l) * DIN] = f2b(yt);
    bq += 256;
  }
}

// ---------------------------------------------------------------- residual + LayerNorm
__global__ __launch_bounds__(256) void residual_ln(
    const float* __restrict__ x, const float* __restrict__ at,
    const float* __restrict__ mb, const float* __restrict__ lw,
    const float* __restrict__ lb, float* __restrict__ out)
{
  int row = blockIdx.x * 4 + (threadIdx.x >> 6);
  int l = threadIdx.x & 63;
  size_t base = (size_t)row * DD;
  float h[8];
  float s = 0.f, s2 = 0.f;
  #pragma unroll
  for (int half = 0; half < 2; half++) {
    int c = half * 256 + l * 4;
    float4 xv = *(const float4*)(x + base + c);
    float4 av = *(const float4*)(at + base + c);
    float4 mv = *(const float4*)(mb + base + c);
    float* hp = h + half * 4;
    hp[0] = xv.x + av.x + mv.x;
    hp[1] = xv.y + av.y + mv.y;
    hp[2] = xv.z + av.z + mv.z;
    hp[3] = xv.w + av.w + mv.w;
    #pragma unroll
    for (int j = 0; j < 4; j++) { s += hp[j]; s2 += hp[j] * hp[j]; }
  }
  #pragma unroll
  for (int o = 1; o < 64; o <<= 1) { s += __shfl_xor(s, o); s2 += __shfl_xor(s2, o); }
  float mean = s * (1.f / DD);
  float var = s2 * (1.f / DD) - mean * mean;
  float rs = rsqrtf(var + 1e-5f);
  #pragma unroll
  for (int half = 0; half < 2; half++) {
    int c = half * 256 + l * 4;
    float4 ov;
    ov.x = (h[half*4+0] - mean) * rs * lw[c+0] + lb[c+0];
    ov.y = (h[half*4+1] - mean) * rs * lw[c+1] + lb[c+1];
    ov.z = (h[half*4+2] - mean) * rs * lw[c+2] + lb[c+2];
    ov.w = (h[half*4+3] - mean) * rs * lw[c+3] + lb[c+3];
    *(float4*)(out + base + c) = ov;
  }
}

// ---------------------------------------------------------------- host
extern "C" void kernel_launch(void* const* d_in, const int* in_sizes, int n_in,
                              void* d_out, int out_size, void* d_ws, size_t ws_size,
                              hipStream_t stream) {
  const float* x    = (const float*)d_in[0];
  const float* wq   = (const float*)d_in[1];
  const float* bq   = (const float*)d_in[2];
  const float* wk   = (const float*)d_in[3];
  const float* bk   = (const float*)d_in[4];
  const float* wv   = (const float*)d_in[5];
  const float* bv   = (const float*)d_in[6];
  const float* wo   = (const float*)d_in[7];
  const float* bo   = (const float*)d_in[8];
  const float* inw  = (const float*)d_in[9];
  const float* cw   = (const float*)d_in[10];
  const float* cb   = (const float*)d_in[11];
  const float* xpw  = (const float*)d_in[12];
  const float* dtw  = (const float*)d_in[13];
  const float* dtb  = (const float*)d_in[14];
  const float* alog = (const float*)d_in[15];
  const float* dpar = (const float*)d_in[16];
  const float* opw  = (const float*)d_in[17];
  const float* lnw  = (const float*)d_in[18];
  const float* lnb  = (const float*)d_in[19];

  char* ws = (char*)d_ws;
  size_t off = 0;
  auto alloc = [&](size_t bytes) -> void* {
    void* p = ws + off;
    off += (bytes + 255) & ~(size_t)255;
    return p;
  };

  const size_t BLD = (size_t)BL * DD;
  const size_t BLDIN = (size_t)BL * DIN;

  ushort* xf_b   = (ushort*)alloc(BLD * 2);
  ushort* wq_b   = (ushort*)alloc(DD * DD * 2);
  ushort* wk_b   = (ushort*)alloc(DD * DD * 2);
  ushort* wv_b   = (ushort*)alloc(DD * DD * 2);
  ushort* wo_b   = (ushort*)alloc(DD * DD * 2);
  ushort* inw_b  = (ushort*)alloc(2 * DIN * DD * 2);
  ushort* xpw_b  = (ushort*)alloc(160 * DIN * 2);
  ushort* dtw_b  = (ushort*)alloc(DIN * RR * 2);
  ushort* opw_b  = (ushort*)alloc(DD * DIN * 2);
  ushort* q_b    = (ushort*)alloc(BLD * 2);
  ushort* k_b    = (ushort*)alloc(BLD * 2);
  ushort* v_b    = (ushort*)alloc(BLD * 2);
  ushort* ctx_b  = (ushort*)alloc(BLD * 2);
  float*  attn_o = (float*)alloc(BLD * 4);
  float*  xz     = (float*)alloc(BL * (size_t)(2 * DIN) * 4);
  float*  u_f    = (float*)alloc(BLDIN * 4);
  ushort* u_b    = (ushort*)alloc(BLDIN * 2);
  float*  dbc    = (float*)alloc((size_t)BL * 160 * 4);
  ushort* dtc_b  = (ushort*)alloc((size_t)BL * RR * 2);
  float*  dt_f   = (float*)alloc(BLDIN * 4);
  ushort* ym_b   = (ushort*)alloc(BLDIN * 2);
  float*  mamba_o= (float*)alloc(BLD * 4);
  float*  bcp    = (float*)alloc((size_t)BB * (LL / 2) * NS * 4 * 4);  // 2.1 MB
  unsigned* dtu_p = (unsigned*)alloc(BLDIN * 4);   // bf16x2, 16.8 MB
  unsigned* sg_p  = (unsigned*)alloc(BLDIN * 4);   // bf16x2, 16.8 MB

  // scan scratch aliased onto xz (xz dead after pack_dtu; phase1 runs later)
  const size_t SCN = (size_t)BB * DIN * NCH * 64;  // 2.1M elems
  float* hf_s    = (float*)xz;
  float* ap_s    = hf_s + SCN;
  float* carry_s = ap_s + SCN;

  // 1) convert inputs to bf16
  CvtJobs cj;
  cj.src[0] = x;    cj.dst[0] = xf_b;  cj.n[0] = (int)BLD;
  cj.src[1] = wq;   cj.dst[1] = wq_b;  cj.n[1] = DD * DD;
  cj.src[2] = wk;   cj.dst[2] = wk_b;  cj.n[2] = DD * DD;
  cj.src[3] = wv;   cj.dst[3] = wv_b;  cj.n[3] = DD * DD;
  cj.src[4] = wo;   cj.dst[4] = wo_b;  cj.n[4] = DD * DD;
  cj.src[5] = inw;  cj.dst[5] = inw_b; cj.n[5] = 2 * DIN * DD;
  cj.src[6] = xpw;  cj.dst[6] = xpw_b; cj.n[6] = 160 * DIN;
  cj.src[7] = dtw;  cj.dst[7] = dtw_b; cj.n[7] = DIN * RR;
  cj.src[8] = opw;  cj.dst[8] = opw_b; cj.n[8] = DD * DIN;
  cvt_multi<<<dim3(256, 9), 256, 0, stream>>>(cj);

  // 2) q,k,v projections
  gemm_bt<<<dim3(8, 64), 256, 0, stream>>>(xf_b, wq_b, bq, nullptr, q_b, BL, DD, DD, 0);
  gemm_bt<<<dim3(8, 64), 256, 0, stream>>>(xf_b, wk_b, bk, nullptr, k_b, BL, DD, DD, 0);
  gemm_bt<<<dim3(8, 64), 256, 0, stream>>>(xf_b, wv_b, bv, nullptr, v_b, BL, DD, DD, 0);

  // 3) flash attention
  flash_attn<<<dim3(32, HH, BB), 256, 0, stream>>>(q_b, k_b, v_b, ctx_b);

  // 4) output projection
  gemm_bt<<<dim3(8, 64), 256, 0, stream>>>(ctx_b, wo_b, bo, attn_o, nullptr, BL, DD, DD, 0);

  // 5) mamba in_proj
  gemm_bt<<<dim3(32, 64), 256, 0, stream>>>(xf_b, inw_b, nullptr, xz, nullptr, BL, 2 * DIN, DD, 0);

  // 6) depthwise conv + SiLU
  conv_silu<<<dim3(32768), 256, 0, stream>>>(xz, cw, cb, u_f, u_b);

  // 7) x_proj
  gemm_bt<<<dim3(3, 64), 256, 0, stream>>>(u_b, xpw_b, nullptr, dbc, nullptr, BL, 160, DIN, 0);

  // 8) dt slice + dt_proj + softplus
  slice_dt<<<dim3(512), 256, 0, stream>>>(dbc, dtc_b);
  gemm_bt<<<dim3(16, 64), 256, 0, stream>>>(dtc_b, dtw_b, dtb, dt_f, nullptr, BL, DIN, RR, 1);

  // 9) pack (B/C and time-major dt/u/gate), then chunked selective scan
  pack_bc<<<dim3(512), 256, 0, stream>>>(dbc, bcp);
  pack_dtu<<<dim3(16, 128), 256, 0, stream>>>(dt_f, u_f, xz, dpar, dtu_p, sg_p);
  scan_phase1<<<dim3(8192), 256, 0, stream>>>(dtu_p, bcp, alog, hf_s, ap_s);
  scan_carry<<<dim3(512), 256, 0, stream>>>(hf_s, ap_s, carry_s);
  scan_phase3<<<dim3(8192), 256, 0, stream>>>(dtu_p, sg_p, bcp, alog, carry_s, ym_b);

  // 10) out_proj
  gemm_bt<<<dim3(8, 64), 256, 0, stream>>>(ym_b, opw_b, nullptr, mamba_o, nullptr, BL, DD, DIN, 0);

  // 11) residual + LayerNorm
  residual_ln<<<dim3(1024), 256, 0, stream>>>(x, attn_o, mamba_o, lnw, lnb, (float*)d_out);
}

// Round 6
// 469.628 us; speedup vs baseline: 3.4034x; 1.3541x over previous
//
#include <hip/hip_runtime.h>

typedef __attribute__((ext_vector_type(4))) float f32x4;
typedef __attribute__((ext_vector_type(8))) short short8;

#define DEV static __device__ __forceinline__

DEV ushort f2b(float f) {
  union { float f; unsigned u; } v; v.f = f;
  unsigned r = v.u + 0x7FFF + ((v.u >> 16) & 1);
  return (ushort)(r >> 16);
}
DEV unsigned pack_bf2(float lo, float hi) {
  return (unsigned)f2b(lo) | ((unsigned)f2b(hi) << 16);
}
DEV float bflo(unsigned p) { return __uint_as_float(p << 16); }
DEV float bfhi(unsigned p) { return __uint_as_float(p & 0xFFFF0000u); }

// raw v_exp_f32 (2^x), no OCML denorm fixup sequence
DEV float fexp2(float x) { float r; asm("v_exp_f32 %0, %1" : "=v"(r) : "v"(x)); return r; }

// DPP helpers (quad_perm / row_shr / row_bcast) and ds_swizzle xor
#define QP(x, ctrl) __int_as_float(__builtin_amdgcn_update_dpp(0, __float_as_int(x), (ctrl), 0xf, 0xf, false))
#define SWZ(x, off) __int_as_float(__builtin_amdgcn_ds_swizzle(__float_as_int(x), (off)))
#define DPP_ADD(x, ctrl, rmask) \
  ((x) + __int_as_float(__builtin_amdgcn_update_dpp(0, __float_as_int(x), (ctrl), (rmask), 0xf, false)))

// ---------------------------------------------------------------- constants
#define BB    2
#define LL    2048
#define DD    512
#define HH    8
#define EE    64
#define DIN   1024
#define NS    64
#define RR    32
#define BL    4096            // B*L
#define NCH   16              // scan chunks
#define TC    128             // steps per chunk (LL/NCH)
#define MFMA(a,b,c) __builtin_amdgcn_mfma_f32_16x16x32_bf16((a),(b),(c),0,0,0)

// ---------------------------------------------------------------- f32 -> bf16 multi-convert
struct CvtJobs {
  const float* src[9];
  ushort*      dst[9];
  int          n[9];
};

__global__ __launch_bounds__(256) void cvt_multi(CvtJobs j) {
  int job = blockIdx.y;
  const float* s = j.src[job];
  ushort* d = j.dst[job];
  int n = j.n[job];
  for (int i = blockIdx.x * 256 + threadIdx.x; i < n; i += gridDim.x * 256)
    d[i] = f2b(s[i]);
}

// ---------------------------------------------------------------- generic GEMM: C = A @ W^T (+bias)(+softplus)
__global__ __launch_bounds__(256) void gemm_bt(
    const ushort* __restrict__ A, const ushort* __restrict__ W,
    const float* __restrict__ bias, float* __restrict__ outF,
    ushort* __restrict__ outB, int M, int N, int K, int act)
{
  __shared__ ushort As[64][40];
  __shared__ ushort Ws[64][40];
  int m0 = blockIdx.y * 64, n0 = blockIdx.x * 64;
  int tid = threadIdx.x, l = tid & 63, w = tid >> 6;
  int wm = (w >> 1) * 32, wn = (w & 1) * 32;
  int lr = l & 15, kl = (l >> 4) * 8;
  int srow = tid >> 2, sk = (tid & 3) * 8;
  f32x4 acc[2][2] = {};

  for (int k0 = 0; k0 < K; k0 += 32) {
    uint4 av = *(const uint4*)&A[(size_t)(m0 + srow) * K + k0 + sk];
    uint4 wv;
    if (n0 + srow < N) wv = *(const uint4*)&W[(size_t)(n0 + srow) * K + k0 + sk];
    else { wv.x = 0; wv.y = 0; wv.z = 0; wv.w = 0; }
    *(uint4*)&As[srow][sk] = av;
    *(uint4*)&Ws[srow][sk] = wv;
    __syncthreads();
    short8 a0 = *(const short8*)&As[wm + lr][kl];
    short8 a1 = *(const short8*)&As[wm + 16 + lr][kl];
    short8 b0 = *(const short8*)&Ws[wn + lr][kl];
    short8 b1 = *(const short8*)&Ws[wn + 16 + lr][kl];
    acc[0][0] = MFMA(a0, b0, acc[0][0]);
    acc[0][1] = MFMA(a0, b1, acc[0][1]);
    acc[1][0] = MFMA(a1, b0, acc[1][0]);
    acc[1][1] = MFMA(a1, b1, acc[1][1]);
    __syncthreads();
  }

  #pragma unroll
  for (int mi = 0; mi < 2; mi++)
    #pragma unroll
    for (int ni = 0; ni < 2; ni++) {
      int rbase = m0 + wm + mi * 16 + ((l >> 4) << 2);
      int col = n0 + wn + ni * 16 + lr;
      if (col < N) {
        float bval = bias ? bias[col] : 0.f;
        #pragma unroll
        for (int r = 0; r < 4; r++) {
          float v = acc[mi][ni][r] + bval;
          if (act == 1) v = (v > 20.f) ? v : log1pf(__expf(v));
          size_t o = (size_t)(rbase + r) * N + col;
          if (outF) outF[o] = v;
          if (outB) outB[o] = f2b(v);
        }
      }
    }
}

// ---------------------------------------------------------------- flash attention (causal, e=64)
__global__ __launch_bounds__(256) void flash_attn(
    const ushort* __restrict__ qb, const ushort* __restrict__ kb,
    const ushort* __restrict__ vb, ushort* __restrict__ ctx)
{
  __shared__ ushort Qs[64][72];
  __shared__ ushort Ks[64][72];
  __shared__ ushort Vt[64][72];
  __shared__ ushort Ps[64][72];

  int qt = blockIdx.x, h = blockIdx.y, b = blockIdx.z;
  int tid = threadIdx.x, l = tid & 63, w = tid >> 6;
  int w16 = w * 16, lr = l & 15, kl = (l >> 4) * 8;

  for (int i = tid; i < 512; i += 256) {
    int row = i >> 3, c8 = (i & 7) * 8;
    *(uint4*)&Qs[row][c8] =
        *(const uint4*)&qb[((size_t)(b * LL + qt * 64 + row)) * DD + h * EE + c8];
  }
  __syncthreads();

  float m_r[4] = {-1e30f, -1e30f, -1e30f, -1e30f};
  float l_r[4] = {0.f, 0.f, 0.f, 0.f};
  f32x4 oacc[4] = {};

  for (int kv = 0; kv <= qt; kv++) {
    for (int i = tid; i < 512; i += 256) {
      int s = i >> 3, c8 = (i & 7) * 8;
      *(uint4*)&Ks[s][c8] =
          *(const uint4*)&kb[((size_t)(b * LL + kv * 64 + s)) * DD + h * EE + c8];
      uint4 vv = *(const uint4*)&vb[((size_t)(b * LL + kv * 64 + s)) * DD + h * EE + c8];
      const ushort* pv = (const ushort*)&vv;
      #pragma unroll
      for (int jj = 0; jj < 8; jj++) Vt[c8 + jj][s] = pv[jj];
    }
    __syncthreads();

    f32x4 sacc[4] = {};
    #pragma unroll
    for (int kk = 0; kk < 2; kk++) {
      short8 aq = *(const short8*)&Qs[w16 + lr][kk * 32 + kl];
      #pragma unroll
      for (int nt = 0; nt < 4; nt++) {
        short8 bk8 = *(const short8*)&Ks[nt * 16 + lr][kk * 32 + kl];
        sacc[nt] = MFMA(aq, bk8, sacc[nt]);
      }
    }

    bool diag = (kv == qt);
    float scl[4];
    #pragma unroll
    for (int r = 0; r < 4; r++) {
      int rloc = w16 + ((l >> 4) << 2) + r;
      float sv[4];
      #pragma unroll
      for (int nt = 0; nt < 4; nt++) {
        float v = sacc[nt][r] * 0.125f;
        if (diag && (nt * 16 + lr) > rloc) v = -1e30f;
        sv[nt] = v;
      }
      float mx = fmaxf(fmaxf(sv[0], sv[1]), fmaxf(sv[2], sv[3]));
      #pragma unroll
      for (int o = 1; o < 16; o <<= 1) mx = fmaxf(mx, __shfl_xor(mx, o));
      float mnew = fmaxf(m_r[r], mx);
      float sc = __expf(m_r[r] - mnew);
      float rs = 0.f;
      #pragma unroll
      for (int nt = 0; nt < 4; nt++) {
        float p = __expf(sv[nt] - mnew);
        rs += p;
        Ps[rloc][nt * 16 + lr] = f2b(p);
      }
      #pragma unroll
      for (int o = 1; o < 16; o <<= 1) rs += __shfl_xor(rs, o);
      l_r[r] = l_r[r] * sc + rs;
      m_r[r] = mnew;
      scl[r] = sc;
    }
    #pragma unroll
    for (int nt = 0; nt < 4; nt++)
      #pragma unroll
      for (int r = 0; r < 4; r++) oacc[nt][r] *= scl[r];

    #pragma unroll
    for (int kk = 0; kk < 2; kk++) {
      short8 ap = *(const short8*)&Ps[w16 + lr][kk * 32 + kl];
      #pragma unroll
      for (int nt = 0; nt < 4; nt++) {
        short8 bv8 = *(const short8*)&Vt[nt * 16 + lr][kk * 32 + kl];
        oacc[nt] = MFMA(ap, bv8, oacc[nt]);
      }
    }
    __syncthreads();
  }

  #pragma unroll
  for (int nt = 0; nt < 4; nt++)
    #pragma unroll
    for (int r = 0; r < 4; r++) {
      int row = qt * 64 + w16 + ((l >> 4) << 2) + r;
      float v = oacc[nt][r] / l_r[r];
      ctx[((size_t)(b * LL + row)) * DD + h * EE + nt * 16 + lr] = f2b(v);
    }
}

// ---------------------------------------------------------------- depthwise causal conv (K=4) + SiLU
__global__ __launch_bounds__(256) void conv_silu(
    const float* __restrict__ xz, const float* __restrict__ cw,
    const float* __restrict__ cb, float* __restrict__ u, ushort* __restrict__ ub)
{
  int i = blockIdx.x * 256 + threadIdx.x;
  if (i >= BL * DIN) return;
  int d = i & (DIN - 1);
  int bl = i >> 10;
  int t = bl & (LL - 1);
  int b = bl >> 11;
  float s = cb[d];
  #pragma unroll
  for (int j = 0; j < 4; j++) {
    int tt = t - 3 + j;
    if (tt >= 0) s += xz[((size_t)(b * LL + tt)) * (2 * DIN) + d] * cw[d * 4 + j];
  }
  float r = s / (1.f + __expf(-s));
  u[i] = r;
  ub[i] = f2b(r);
}

// ---------------------------------------------------------------- slice dbc[:, :32] -> bf16
__global__ __launch_bounds__(256) void slice_dt(
    const float* __restrict__ dbc, ushort* __restrict__ dtc)
{
  int i = blockIdx.x * 256 + threadIdx.x;
  if (i >= BL * RR) return;
  int m = i >> 5, r = i & 31;
  dtc[i] = f2b(dbc[m * 160 + r]);
}

// ---------------------------------------------------------------- pack B,C
// bbp[b][tp][n]  = bf16x2 {B_2tp, B_2tp+1}          (phase 1, B only)
// bcp2[b][t][n]  = float2 {B_t, C_t}                 (phase 3)
__global__ __launch_bounds__(256) void pack_bc(
    const float* __restrict__ dbc, unsigned* __restrict__ bbp,
    float2* __restrict__ bcp2)
{
  int i = blockIdx.x * 256 + threadIdx.x;     // (b, tp, n): BB*1024*64
  if (i >= BB * (LL / 2) * NS) return;
  int n = i & 63, tp = (i >> 6) & 1023, b = i >> 16;
  size_t r0 = ((size_t)(b * LL + 2 * tp)) * 160;
  float B0 = dbc[r0 + 32 + n],       C0 = dbc[r0 + 96 + n];
  float B1 = dbc[r0 + 160 + 32 + n], C1 = dbc[r0 + 160 + 96 + n];
  bbp[i] = pack_bf2(B0, B1);
  size_t o2 = ((size_t)(b * LL + 2 * tp)) * 64 + n;
  bcp2[o2]      = make_float2(B0, C0);
  bcp2[o2 + 64] = make_float2(B1, C1);
}

// ---------------------------------------------------------------- pack dt/u/z: time-major bf16x2 arrays
// dtu_p[(b*DIN+d)*LL+t] = {dt, dt*u};  sg_p[...] = {gz, u*D*gz}
__global__ __launch_bounds__(256) void pack_dtu(
    const float* __restrict__ dtf, const float* __restrict__ uf,
    const float* __restrict__ xz, const float* __restrict__ dpar,
    unsigned* __restrict__ dtu_p, unsigned* __restrict__ sg_p)
{
  __shared__ float s_dt[32][65], s_du[32][65], s_gz[32][65], s_ug[32][65];
  int d0 = blockIdx.x * 64, t0 = blockIdx.y * 32;
  int tid = threadIdx.x;
  int c = tid & 63, r4 = tid >> 6;
  float Dv = dpar[d0 + c];
  #pragma unroll
  for (int k = 0; k < 8; k++) {
    int r = k * 4 + r4;
    size_t row = (size_t)(t0 + r);
    float dtv = dtf[row * DIN + d0 + c];
    float uv  = uf [row * DIN + d0 + c];
    float zz  = xz [row * (2 * DIN) + DIN + d0 + c];
    float g = zz / (1.f + __expf(-zz));
    s_dt[r][c] = dtv;
    s_du[r][c] = dtv * uv;
    s_gz[r][c] = g;
    s_ug[r][c] = uv * Dv * g;
  }
  __syncthreads();
  int dl = tid >> 2, q = tid & 3;
  int b = t0 >> 11, tl0 = t0 & (LL - 1);
  size_t obase = ((size_t)(b * DIN + d0 + dl)) * LL + tl0 + q * 8;
  #pragma unroll
  for (int tt = 0; tt < 8; tt++) {
    int t = q * 8 + tt;
    dtu_p[obase + tt] = pack_bf2(s_dt[t][dl], s_du[t][dl]);
    sg_p [obase + tt] = pack_bf2(s_gz[t][dl], s_ug[t][dl]);
  }
}

// ---------------------------------------------------------------- chunked scan, phase 1 (suffix-sum form, no recurrence)
// h_final = sum_s exp(An * E_s) * dtu_s * B_s,  E_s = sum_{tau>s} dt_tau
__global__ __launch_bounds__(256) void scan_phase1(
    const unsigned* __restrict__ dtu_p, const unsigned* __restrict__ bbp,
    const float* __restrict__ alog, float* __restrict__ hf, float* __restrict__ ap)
{
  __shared__ float lds[4][TC][2];
  int tid = threadIdx.x, w = tid >> 6, l = tid & 63;
  int wid = blockIdx.x * 4 + w;
  int d = wid & (DIN - 1);
  int c = (wid >> 10) & (NCH - 1);
  int b = wid >> 14;
  float An2 = -__expf(alog[d * NS + l]) * 1.44269504f;

  size_t pbase = ((size_t)(b * DIN + d)) * LL + c * TC;
  unsigned p0 = dtu_p[pbase + l];
  unsigned p1 = dtu_p[pbase + 64 + l];
  float s0 = bflo(p0), s1 = bflo(p1);
  // wave64 inclusive prefix scans (DPP)
  s0 = DPP_ADD(s0, 0x111, 0xf); s0 = DPP_ADD(s0, 0x112, 0xf);
  s0 = DPP_ADD(s0, 0x114, 0xf); s0 = DPP_ADD(s0, 0x118, 0xf);
  s0 = DPP_ADD(s0, 0x142, 0xa); s0 = DPP_ADD(s0, 0x143, 0xc);
  s1 = DPP_ADD(s1, 0x111, 0xf); s1 = DPP_ADD(s1, 0x112, 0xf);
  s1 = DPP_ADD(s1, 0x114, 0xf); s1 = DPP_ADD(s1, 0x118, 0xf);
  s1 = DPP_ADD(s1, 0x142, 0xa); s1 = DPP_ADD(s1, 0x143, 0xc);
  float T0 = __uint_as_float(__builtin_amdgcn_readlane(__float_as_uint(s0), 63));
  float T  = T0 + __uint_as_float(__builtin_amdgcn_readlane(__float_as_uint(s1), 63));
  lds[w][l][0]      = T - s0;          // E_t for t = l
  lds[w][l][1]      = bfhi(p0);        // dtu_t
  lds[w][64 + l][0] = (T - T0) - s1;   // E_t for t = 64+l
  lds[w][64 + l][1] = bfhi(p1);
  __syncthreads();

  const unsigned* bq = bbp + ((size_t)(b * 1024 + c * 64) * 64 + l);
  float h0 = 0.f, h1 = 0.f;
  unsigned bb[4] = {bq[0], bq[64], bq[128], bq[192]};
  for (int g = 0; g < 16; g++) {
    unsigned nb[4] = {bb[0], bb[1], bb[2], bb[3]};
    if (g < 15) {
      const unsigned* q = bq + 256;
      nb[0] = q[0]; nb[1] = q[64]; nb[2] = q[128]; nb[3] = q[192];
    }
    const float* gb = &lds[w][g * 8][0];
    #pragma unroll
    for (int j = 0; j < 8; j++) {
      float2 dd = *(const float2*)(gb + j * 2);
      float Bv = (j & 1) ? bfhi(bb[j >> 1]) : bflo(bb[j >> 1]);
      float a = fexp2(dd.x * An2);
      if (j & 1) h1 += a * (dd.y * Bv);
      else       h0 += a * (dd.y * Bv);
    }
    bb[0] = nb[0]; bb[1] = nb[1]; bb[2] = nb[2]; bb[3] = nb[3];
    bq += 256;
  }
  size_t o = (((size_t)((b << 10) + d) * NCH) + c) * 64 + l;
  hf[o] = h0 + h1;
  ap[o] = fexp2(T * An2);
}

// ---------------------------------------------------------------- chunked scan, phase 2 (carry combine)
__global__ __launch_bounds__(256) void scan_carry(
    const float* __restrict__ hf, const float* __restrict__ ap,
    float* __restrict__ carry)
{
  int i = blockIdx.x * 256 + threadIdx.x;   // (b, d, n)
  int n = i & 63;
  int d = (i >> 6) & (DIN - 1);
  int b = i >> 16;
  size_t base = ((size_t)((b << 10) + d) * NCH) * 64 + n;
  float cur = 0.f;
  #pragma unroll
  for (int c = 0; c < NCH; c++) {
    carry[base + (size_t)c * 64] = cur;
    cur = ap[base + (size_t)c * 64] * cur + hf[base + (size_t)c * 64];
  }
}

// ---------------------------------------------------------------- chunked scan, phase 3
// recurrence + batched-8 deferred reduce; raw v_exp; reg-dbuf B/C loads.
__global__ __launch_bounds__(256) void scan_phase3(
    const unsigned* __restrict__ dtu_p, const unsigned* __restrict__ sg_p,
    const float2* __restrict__ bcp2, const float* __restrict__ alog,
    const float* __restrict__ carry, ushort* __restrict__ ymb)
{
  __shared__ float lds[4][TC][4];
  int tid = threadIdx.x, w = tid >> 6, l = tid & 63;
  int wid = blockIdx.x * 4 + w;
  int d = wid & (DIN - 1);
  int c = (wid >> 10) & (NCH - 1);
  int b = wid >> 14;
  float An2 = -__expf(alog[d * NS + l]) * 1.44269504f;

  size_t pbase = ((size_t)(b * DIN + d)) * LL + c * TC;
  #pragma unroll
  for (int q = 0; q < 2; q++) {
    unsigned pd = dtu_p[pbase + q * 64 + l];
    unsigned pg = sg_p [pbase + q * 64 + l];
    lds[w][q * 64 + l][0] = bflo(pd);
    lds[w][q * 64 + l][1] = bfhi(pd);
    lds[w][q * 64 + l][2] = bflo(pg);
    lds[w][q * 64 + l][3] = bfhi(pg);
  }
  __syncthreads();

  size_t rowb = (size_t)(b * LL + c * TC);
  float h = carry[(((size_t)((b << 10) + d) * NCH) + c) * 64 + l];
  const float2* bq = bcp2 + ((size_t)(b * LL + c * TC)) * 64 + l;
  ushort* ym0 = ymb + rowb * DIN + d;
  bool s1f = l & 1, s2f = l & 2, s4f = l & 4;
  bool wl = l < 8;

  float2 bc[8];
  #pragma unroll
  for (int k = 0; k < 8; k++) bc[k] = bq[k * 64];

  for (int g = 0; g < 16; g++) {
    float2 bn[8];
    #pragma unroll
    for (int k = 0; k < 8; k++) bn[k] = bc[k];
    if (g < 15) {
      const float2* qn = bq + 512;
      #pragma unroll
      for (int k = 0; k < 8; k++) bn[k] = qn[k * 64];
    }
    const float* gb = &lds[w][g * 8][0];
    float p[8];
    #pragma unroll
    for (int j = 0; j < 8; j++) {
      float2 dd = *(const float2*)(gb + j * 4);
      float a = fexp2(dd.x * An2);
      h = a * h + dd.y * bc[j].x;
      p[j] = h * bc[j].y;
    }
    // batched 8-sum reduce over 64 lanes: lane l ends with S_{l&7}
    #pragma unroll
    for (int j = 0; j < 8; j++) p[j] += QP(p[j], 0xB1);       // xor1
    float q0 = s1f ? p[1] : p[0];
    float q1 = s1f ? p[3] : p[2];
    float q2 = s1f ? p[5] : p[4];
    float q3 = s1f ? p[7] : p[6];
    q0 += QP(q0, 0x4E); q1 += QP(q1, 0x4E);                   // xor2
    q2 += QP(q2, 0x4E); q3 += QP(q3, 0x4E);
    float r0 = s2f ? q1 : q0;
    float r1 = s2f ? q3 : q2;
    r0 += SWZ(r0, 0x101F); r1 += SWZ(r1, 0x101F);             // xor4
    float s = s4f ? r1 : r0;
    s += QP(s, 0x128);                                        // xor8 (row_ror:8)
    s += SWZ(s, 0x401F);                                      // xor16
    s += __shfl_xor(s, 32);                                   // xor32

    float2 sgv = *(const float2*)(&lds[w][g * 8 + (l & 7)][2]);
    float yt = s * sgv.x + sgv.y;
    if (wl) ym0[(g * 8 + l) * DIN] = f2b(yt);
    #pragma unroll
    for (int k = 0; k < 8; k++) bc[k] = bn[k];
    bq += 512;
  }
}

// ---------------------------------------------------------------- residual + LayerNorm
__global__ __launch_bounds__(256) void residual_ln(
    const float* __restrict__ x, const float* __restrict__ at,
    const float* __restrict__ mb, const float* __restrict__ lw,
    const float* __restrict__ lb, float* __restrict__ out)
{
  int row = blockIdx.x * 4 + (threadIdx.x >> 6);
  int l = threadIdx.x & 63;
  size_t base = (size_t)row * DD;
  float h[8];
  float s = 0.f, s2 = 0.f;
  #pragma unroll
  for (int half = 0; half < 2; half++) {
    int c = half * 256 + l * 4;
    float4 xv = *(const float4*)(x + base + c);
    float4 av = *(const float4*)(at + base + c);
    float4 mv = *(const float4*)(mb + base + c);
    float* hp = h + half * 4;
    hp[0] = xv.x + av.x + mv.x;
    hp[1] = xv.y + av.y + mv.y;
    hp[2] = xv.z + av.z + mv.z;
    hp[3] = xv.w + av.w + mv.w;
    #pragma unroll
    for (int j = 0; j < 4; j++) { s += hp[j]; s2 += hp[j] * hp[j]; }
  }
  #pragma unroll
  for (int o = 1; o < 64; o <<= 1) { s += __shfl_xor(s, o); s2 += __shfl_xor(s2, o); }
  float mean = s * (1.f / DD);
  float var = s2 * (1.f / DD) - mean * mean;
  float rs = rsqrtf(var + 1e-5f);
  #pragma unroll
  for (int half = 0; half < 2; half++) {
    int c = half * 256 + l * 4;
    float4 ov;
    ov.x = (h[half*4+0] - mean) * rs * lw[c+0] + lb[c+0];
    ov.y = (h[half*4+1] - mean) * rs * lw[c+1] + lb[c+1];
    ov.z = (h[half*4+2] - mean) * rs * lw[c+2] + lb[c+2];
    ov.w = (h[half*4+3] - mean) * rs * lw[c+3] + lb[c+3];
    *(float4*)(out + base + c) = ov;
  }
}

// ---------------------------------------------------------------- host
extern "C" void kernel_launch(void* const* d_in, const int* in_sizes, int n_in,
                              void* d_out, int out_size, void* d_ws, size_t ws_size,
                              hipStream_t stream) {
  const float* x    = (const float*)d_in[0];
  const float* wq   = (const float*)d_in[1];
  const float* bq   = (const float*)d_in[2];
  const float* wk   = (const float*)d_in[3];
  const float* bk   = (const float*)d_in[4];
  const float* wv   = (const float*)d_in[5];
  const float* bv   = (const float*)d_in[6];
  const float* wo   = (const float*)d_in[7];
  const float* bo   = (const float*)d_in[8];
  const float* inw  = (const float*)d_in[9];
  const float* cw   = (const float*)d_in[10];
  const float* cb   = (const float*)d_in[11];
  const float* xpw  = (const float*)d_in[12];
  const float* dtw  = (const float*)d_in[13];
  const float* dtb  = (const float*)d_in[14];
  const float* alog = (const float*)d_in[15];
  const float* dpar = (const float*)d_in[16];
  const float* opw  = (const float*)d_in[17];
  const float* lnw  = (const float*)d_in[18];
  const float* lnb  = (const float*)d_in[19];

  char* ws = (char*)d_ws;
  size_t off = 0;
  auto alloc = [&](size_t bytes) -> void* {
    void* p = ws + off;
    off += (bytes + 255) & ~(size_t)255;
    return p;
  };

  const size_t BLD = (size_t)BL * DD;
  const size_t BLDIN = (size_t)BL * DIN;

  ushort* xf_b   = (ushort*)alloc(BLD * 2);
  ushort* wq_b   = (ushort*)alloc(DD * DD * 2);
  ushort* wk_b   = (ushort*)alloc(DD * DD * 2);
  ushort* wv_b   = (ushort*)alloc(DD * DD * 2);
  ushort* wo_b   = (ushort*)alloc(DD * DD * 2);
  ushort* inw_b  = (ushort*)alloc(2 * DIN * DD * 2);
  ushort* xpw_b  = (ushort*)alloc(160 * DIN * 2);
  ushort* dtw_b  = (ushort*)alloc(DIN * RR * 2);
  ushort* opw_b  = (ushort*)alloc(DD * DIN * 2);
  ushort* q_b    = (ushort*)alloc(BLD * 2);
  ushort* k_b    = (ushort*)alloc(BLD * 2);
  ushort* v_b    = (ushort*)alloc(BLD * 2);
  ushort* ctx_b  = (ushort*)alloc(BLD * 2);
  float*  attn_o = (float*)alloc(BLD * 4);
  float*  xz     = (float*)alloc(BL * (size_t)(2 * DIN) * 4);
  float*  u_f    = (float*)alloc(BLDIN * 4);
  ushort* u_b    = (ushort*)alloc(BLDIN * 2);
  float*  dbc    = (float*)alloc((size_t)BL * 160 * 4);
  ushort* dtc_b  = (ushort*)alloc((size_t)BL * RR * 2);
  float*  dt_f   = (float*)alloc(BLDIN * 4);
  ushort* ym_b   = (ushort*)alloc(BLDIN * 2);
  float*  mamba_o= (float*)alloc(BLD * 4);
  unsigned* bbp  = (unsigned*)alloc((size_t)BB * (LL / 2) * NS * 4);      // 0.5 MB
  float2* bcp2   = (float2*)alloc((size_t)BB * LL * NS * sizeof(float2)); // 2.1 MB
  unsigned* dtu_p = (unsigned*)alloc(BLDIN * 4);   // bf16x2, 16.8 MB
  unsigned* sg_p  = (unsigned*)alloc(BLDIN * 4);   // bf16x2, 16.8 MB

  // scan scratch aliased onto xz (xz dead after pack_dtu; phase1 runs later)
  const size_t SCN = (size_t)BB * DIN * NCH * 64;  // 2.1M elems
  float* hf_s    = (float*)xz;
  float* ap_s    = hf_s + SCN;
  float* carry_s = ap_s + SCN;

  // 1) convert inputs to bf16
  CvtJobs cj;
  cj.src[0] = x;    cj.dst[0] = xf_b;  cj.n[0] = (int)BLD;
  cj.src[1] = wq;   cj.dst[1] = wq_b;  cj.n[1] = DD * DD;
  cj.src[2] = wk;   cj.dst[2] = wk_b;  cj.n[2] = DD * DD;
  cj.src[3] = wv;   cj.dst[3] = wv_b;  cj.n[3] = DD * DD;
  cj.src[4] = wo;   cj.dst[4] = wo_b;  cj.n[4] = DD * DD;
  cj.src[5] = inw;  cj.dst[5] = inw_b; cj.n[5] = 2 * DIN * DD;
  cj.src[6] = xpw;  cj.dst[6] = xpw_b; cj.n[6] = 160 * DIN;
  cj.src[7] = dtw;  cj.dst[7] = dtw_b; cj.n[7] = DIN * RR;
  cj.src[8] = opw;  cj.dst[8] = opw_b; cj.n[8] = DD * DIN;
  cvt_multi<<<dim3(256, 9), 256, 0, stream>>>(cj);

  // 2) q,k,v projections
  gemm_bt<<<dim3(8, 64), 256, 0, stream>>>(xf_b, wq_b, bq, nullptr, q_b, BL, DD, DD, 0);
  gemm_bt<<<dim3(8, 64), 256, 0, stream>>>(xf_b, wk_b, bk, nullptr, k_b, BL, DD, DD, 0);
  gemm_bt<<<dim3(8, 64), 256, 0, stream>>>(xf_b, wv_b, bv, nullptr, v_b, BL, DD, DD, 0);

  // 3) flash attention
  flash_attn<<<dim3(32, HH, BB), 256, 0, stream>>>(q_b, k_b, v_b, ctx_b);

  // 4) output projection
  gemm_bt<<<dim3(8, 64), 256, 0, stream>>>(ctx_b, wo_b, bo, attn_o, nullptr, BL, DD, DD, 0);

  // 5) mamba in_proj
  gemm_bt<<<dim3(32, 64), 256, 0, stream>>>(xf_b, inw_b, nullptr, xz, nullptr, BL, 2 * DIN, DD, 0);

  // 6) depthwise conv + SiLU
  conv_silu<<<dim3(32768), 256, 0, stream>>>(xz, cw, cb, u_f, u_b);

  // 7) x_proj
  gemm_bt<<<dim3(3, 64), 256, 0, stream>>>(u_b, xpw_b, nullptr, dbc, nullptr, BL, 160, DIN, 0);

  // 8) dt slice + dt_proj + softplus
  slice_dt<<<dim3(512), 256, 0, stream>>>(dbc, dtc_b);
  gemm_bt<<<dim3(16, 64), 256, 0, stream>>>(dtc_b, dtw_b, dtb, dt_f, nullptr, BL, DIN, RR, 1);

  // 9) pack (B/C and time-major dt/u/gate), then chunked selective scan
  pack_bc<<<dim3(512), 256, 0, stream>>>(dbc, bbp, bcp2);
  pack_dtu<<<dim3(16, 128), 256, 0, stream>>>(dt_f, u_f, xz, dpar, dtu_p, sg_p);
  scan_phase1<<<dim3(8192), 256, 0, stream>>>(dtu_p, bbp, alog, hf_s, ap_s);
  scan_carry<<<dim3(512), 256, 0, stream>>>(hf_s, ap_s, carry_s);
  scan_phase3<<<dim3(8192), 256, 0, stream>>>(dtu_p, sg_p, bcp2, alog, carry_s, ym_b);

  // 10) out_proj
  gemm_bt<<<dim3(8, 64), 256, 0, stream>>>(ym_b, opw_b, nullptr, mamba_o, nullptr, BL, DD, DIN, 0);

  // 11) residual + LayerNorm
  residual_ln<<<dim3(1024), 256, 0, stream>>>(x, attn_o, mamba_o, lnw, lnb, (float*)d_out);
}

// Round 7
// 457.875 us; speedup vs baseline: 3.4908x; 1.0257x over previous
//
#include <hip/hip_runtime.h>

typedef __attribute__((ext_vector_type(4))) float f32x4;
typedef __attribute__((ext_vector_type(8))) short short8;

#define DEV static __device__ __forceinline__

DEV ushort f2b(float f) {
  union { float f; unsigned u; } v; v.f = f;
  unsigned r = v.u + 0x7FFF + ((v.u >> 16) & 1);
  return (ushort)(r >> 16);
}
DEV unsigned pack_bf2(float lo, float hi) {
  return (unsigned)f2b(lo) | ((unsigned)f2b(hi) << 16);
}
DEV float bflo(unsigned p) { return __uint_as_float(p << 16); }
DEV float bfhi(unsigned p) { return __uint_as_float(p & 0xFFFF0000u); }

// raw v_exp_f32 (2^x), no OCML denorm fixup sequence
DEV float fexp2(float x) { float r; asm("v_exp_f32 %0, %1" : "=v"(r) : "v"(x)); return r; }

// DPP helpers (quad_perm / row_ror / row_bcast) and ds_swizzle xor
#define QP(x, ctrl) __int_as_float(__builtin_amdgcn_update_dpp(0, __float_as_int(x), (ctrl), 0xf, 0xf, false))
#define SWZ(x, off) __int_as_float(__builtin_amdgcn_ds_swizzle(__float_as_int(x), (off)))
#define DPP_ADD(x, ctrl, rmask) \
  ((x) + __int_as_float(__builtin_amdgcn_update_dpp(0, __float_as_int(x), (ctrl), (rmask), 0xf, false)))

// ---------------------------------------------------------------- constants
#define BB    2
#define LL    2048
#define DD    512
#define HH    8
#define EE    64
#define DIN   1024
#define NS    64
#define RR    32
#define BL    4096            // B*L
#define NCH   16              // scan chunks
#define TC    128             // steps per chunk (LL/NCH)
#define MFMA(a,b,c) __builtin_amdgcn_mfma_f32_16x16x32_bf16((a),(b),(c),0,0,0)

// ---------------------------------------------------------------- f32 -> bf16 multi-convert
struct CvtJobs {
  const float* src[9];
  ushort*      dst[9];
  int          n[9];
};

__global__ __launch_bounds__(256) void cvt_multi(CvtJobs j) {
  int job = blockIdx.y;
  const float* s = j.src[job];
  ushort* d = j.dst[job];
  int n = j.n[job];
  for (int i = blockIdx.x * 256 + threadIdx.x; i < n; i += gridDim.x * 256)
    d[i] = f2b(s[i]);
}

// ---------------------------------------------------------------- generic GEMM: C = A @ W^T (+bias)(+softplus)
__global__ __launch_bounds__(256) void gemm_bt(
    const ushort* __restrict__ A, const ushort* __restrict__ W,
    const float* __restrict__ bias, float* __restrict__ outF,
    ushort* __restrict__ outB, int M, int N, int K, int act)
{
  __shared__ ushort As[64][40];
  __shared__ ushort Ws[64][40];
  int m0 = blockIdx.y * 64, n0 = blockIdx.x * 64;
  int tid = threadIdx.x, l = tid & 63, w = tid >> 6;
  int wm = (w >> 1) * 32, wn = (w & 1) * 32;
  int lr = l & 15, kl = (l >> 4) * 8;
  int srow = tid >> 2, sk = (tid & 3) * 8;
  f32x4 acc[2][2] = {};

  for (int k0 = 0; k0 < K; k0 += 32) {
    uint4 av = *(const uint4*)&A[(size_t)(m0 + srow) * K + k0 + sk];
    uint4 wv;
    if (n0 + srow < N) wv = *(const uint4*)&W[(size_t)(n0 + srow) * K + k0 + sk];
    else { wv.x = 0; wv.y = 0; wv.z = 0; wv.w = 0; }
    *(uint4*)&As[srow][sk] = av;
    *(uint4*)&Ws[srow][sk] = wv;
    __syncthreads();
    short8 a0 = *(const short8*)&As[wm + lr][kl];
    short8 a1 = *(const short8*)&As[wm + 16 + lr][kl];
    short8 b0 = *(const short8*)&Ws[wn + lr][kl];
    short8 b1 = *(const short8*)&Ws[wn + 16 + lr][kl];
    acc[0][0] = MFMA(a0, b0, acc[0][0]);
    acc[0][1] = MFMA(a0, b1, acc[0][1]);
    acc[1][0] = MFMA(a1, b0, acc[1][0]);
    acc[1][1] = MFMA(a1, b1, acc[1][1]);
    __syncthreads();
  }

  #pragma unroll
  for (int mi = 0; mi < 2; mi++)
    #pragma unroll
    for (int ni = 0; ni < 2; ni++) {
      int rbase = m0 + wm + mi * 16 + ((l >> 4) << 2);
      int col = n0 + wn + ni * 16 + lr;
      if (col < N) {
        float bval = bias ? bias[col] : 0.f;
        #pragma unroll
        for (int r = 0; r < 4; r++) {
          float v = acc[mi][ni][r] + bval;
          if (act == 1) v = (v > 20.f) ? v : log1pf(__expf(v));
          size_t o = (size_t)(rbase + r) * N + col;
          if (outF) outF[o] = v;
          if (outB) outB[o] = f2b(v);
        }
      }
    }
}

// ---------------------------------------------------------------- flash attention (causal, e=64)
__global__ __launch_bounds__(256) void flash_attn(
    const ushort* __restrict__ qb, const ushort* __restrict__ kb,
    const ushort* __restrict__ vb, ushort* __restrict__ ctx)
{
  __shared__ ushort Qs[64][72];
  __shared__ ushort Ks[64][72];
  __shared__ ushort Vt[64][72];
  __shared__ ushort Ps[64][72];

  int qt = blockIdx.x, h = blockIdx.y, b = blockIdx.z;
  int tid = threadIdx.x, l = tid & 63, w = tid >> 6;
  int w16 = w * 16, lr = l & 15, kl = (l >> 4) * 8;

  for (int i = tid; i < 512; i += 256) {
    int row = i >> 3, c8 = (i & 7) * 8;
    *(uint4*)&Qs[row][c8] =
        *(const uint4*)&qb[((size_t)(b * LL + qt * 64 + row)) * DD + h * EE + c8];
  }
  __syncthreads();

  float m_r[4] = {-1e30f, -1e30f, -1e30f, -1e30f};
  float l_r[4] = {0.f, 0.f, 0.f, 0.f};
  f32x4 oacc[4] = {};

  for (int kv = 0; kv <= qt; kv++) {
    for (int i = tid; i < 512; i += 256) {
      int s = i >> 3, c8 = (i & 7) * 8;
      *(uint4*)&Ks[s][c8] =
          *(const uint4*)&kb[((size_t)(b * LL + kv * 64 + s)) * DD + h * EE + c8];
      uint4 vv = *(const uint4*)&vb[((size_t)(b * LL + kv * 64 + s)) * DD + h * EE + c8];
      const ushort* pv = (const ushort*)&vv;
      #pragma unroll
      for (int jj = 0; jj < 8; jj++) Vt[c8 + jj][s] = pv[jj];
    }
    __syncthreads();

    f32x4 sacc[4] = {};
    #pragma unroll
    for (int kk = 0; kk < 2; kk++) {
      short8 aq = *(const short8*)&Qs[w16 + lr][kk * 32 + kl];
      #pragma unroll
      for (int nt = 0; nt < 4; nt++) {
        short8 bk8 = *(const short8*)&Ks[nt * 16 + lr][kk * 32 + kl];
        sacc[nt] = MFMA(aq, bk8, sacc[nt]);
      }
    }

    bool diag = (kv == qt);
    float scl[4];
    #pragma unroll
    for (int r = 0; r < 4; r++) {
      int rloc = w16 + ((l >> 4) << 2) + r;
      float sv[4];
      #pragma unroll
      for (int nt = 0; nt < 4; nt++) {
        float v = sacc[nt][r] * 0.125f;
        if (diag && (nt * 16 + lr) > rloc) v = -1e30f;
        sv[nt] = v;
      }
      float mx = fmaxf(fmaxf(sv[0], sv[1]), fmaxf(sv[2], sv[3]));
      #pragma unroll
      for (int o = 1; o < 16; o <<= 1) mx = fmaxf(mx, __shfl_xor(mx, o));
      float mnew = fmaxf(m_r[r], mx);
      float sc = __expf(m_r[r] - mnew);
      float rs = 0.f;
      #pragma unroll
      for (int nt = 0; nt < 4; nt++) {
        float p = __expf(sv[nt] - mnew);
        rs += p;
        Ps[rloc][nt * 16 + lr] = f2b(p);
      }
      #pragma unroll
      for (int o = 1; o < 16; o <<= 1) rs += __shfl_xor(rs, o);
      l_r[r] = l_r[r] * sc + rs;
      m_r[r] = mnew;
      scl[r] = sc;
    }
    #pragma unroll
    for (int nt = 0; nt < 4; nt++)
      #pragma unroll
      for (int r = 0; r < 4; r++) oacc[nt][r] *= scl[r];

    #pragma unroll
    for (int kk = 0; kk < 2; kk++) {
      short8 ap = *(const short8*)&Ps[w16 + lr][kk * 32 + kl];
      #pragma unroll
      for (int nt = 0; nt < 4; nt++) {
        short8 bv8 = *(const short8*)&Vt[nt * 16 + lr][kk * 32 + kl];
        oacc[nt] = MFMA(ap, bv8, oacc[nt]);
      }
    }
    __syncthreads();
  }

  #pragma unroll
  for (int nt = 0; nt < 4; nt++)
    #pragma unroll
    for (int r = 0; r < 4; r++) {
      int row = qt * 64 + w16 + ((l >> 4) << 2) + r;
      float v = oacc[nt][r] / l_r[r];
      ctx[((size_t)(b * LL + row)) * DD + h * EE + nt * 16 + lr] = f2b(v);
    }
}

// ---------------------------------------------------------------- depthwise causal conv (K=4) + SiLU
__global__ __launch_bounds__(256) void conv_silu(
    const float* __restrict__ xz, const float* __restrict__ cw,
    const float* __restrict__ cb, float* __restrict__ u, ushort* __restrict__ ub)
{
  int i = blockIdx.x * 256 + threadIdx.x;
  if (i >= BL * DIN) return;
  int d = i & (DIN - 1);
  int bl = i >> 10;
  int t = bl & (LL - 1);
  int b = bl >> 11;
  float s = cb[d];
  #pragma unroll
  for (int j = 0; j < 4; j++) {
    int tt = t - 3 + j;
    if (tt >= 0) s += xz[((size_t)(b * LL + tt)) * (2 * DIN) + d] * cw[d * 4 + j];
  }
  float r = s / (1.f + __expf(-s));
  u[i] = r;
  ub[i] = f2b(r);
}

// ---------------------------------------------------------------- slice dbc[:, :32] -> bf16
__global__ __launch_bounds__(256) void slice_dt(
    const float* __restrict__ dbc, ushort* __restrict__ dtc)
{
  int i = blockIdx.x * 256 + threadIdx.x;
  if (i >= BL * RR) return;
  int m = i >> 5, r = i & 31;
  dtc[i] = f2b(dbc[m * 160 + r]);
}

// ---------------------------------------------------------------- pack B,C
// bbp[b][tp][n]  = bf16x2 {B_2tp, B_2tp+1}          (phase 1, B only)
// bcp2[b][t][n]  = float2 {B_t, C_t}                 (phase 3)
__global__ __launch_bounds__(256) void pack_bc(
    const float* __restrict__ dbc, unsigned* __restrict__ bbp,
    float2* __restrict__ bcp2)
{
  int i = blockIdx.x * 256 + threadIdx.x;     // (b, tp, n): BB*1024*64
  if (i >= BB * (LL / 2) * NS) return;
  int n = i & 63, tp = (i >> 6) & 1023, b = i >> 16;
  size_t r0 = ((size_t)(b * LL + 2 * tp)) * 160;
  float B0 = dbc[r0 + 32 + n],       C0 = dbc[r0 + 96 + n];
  float B1 = dbc[r0 + 160 + 32 + n], C1 = dbc[r0 + 160 + 96 + n];
  bbp[i] = pack_bf2(B0, B1);
  size_t o2 = ((size_t)(b * LL + 2 * tp)) * 64 + n;
  bcp2[o2]      = make_float2(B0, C0);
  bcp2[o2 + 64] = make_float2(B1, C1);
}

// ---------------------------------------------------------------- pack dt/u/z: time-major bf16x2 arrays
// dtu_p[(b*DIN+d)*LL+t] = {dt, dt*u};  sg_p[...] = {gz, u*D*gz}
__global__ __launch_bounds__(256) void pack_dtu(
    const float* __restrict__ dtf, const float* __restrict__ uf,
    const float* __restrict__ xz, const float* __restrict__ dpar,
    unsigned* __restrict__ dtu_p, unsigned* __restrict__ sg_p)
{
  __shared__ float s_dt[32][65], s_du[32][65], s_gz[32][65], s_ug[32][65];
  int d0 = blockIdx.x * 64, t0 = blockIdx.y * 32;
  int tid = threadIdx.x;
  int c = tid & 63, r4 = tid >> 6;
  float Dv = dpar[d0 + c];
  #pragma unroll
  for (int k = 0; k < 8; k++) {
    int r = k * 4 + r4;
    size_t row = (size_t)(t0 + r);
    float dtv = dtf[row * DIN + d0 + c];
    float uv  = uf [row * DIN + d0 + c];
    float zz  = xz [row * (2 * DIN) + DIN + d0 + c];
    float g = zz / (1.f + __expf(-zz));
    s_dt[r][c] = dtv;
    s_du[r][c] = dtv * uv;
    s_gz[r][c] = g;
    s_ug[r][c] = uv * Dv * g;
  }
  __syncthreads();
  int dl = tid >> 2, q = tid & 3;
  int b = t0 >> 11, tl0 = t0 & (LL - 1);
  size_t obase = ((size_t)(b * DIN + d0 + dl)) * LL + tl0 + q * 8;
  #pragma unroll
  for (int tt = 0; tt < 8; tt++) {
    int t = q * 8 + tt;
    dtu_p[obase + tt] = pack_bf2(s_dt[t][dl], s_du[t][dl]);
    sg_p [obase + tt] = pack_bf2(s_gz[t][dl], s_ug[t][dl]);
  }
}

// ---------------------------------------------------------------- chunked scan, phase 1 (suffix-sum form, no recurrence)
// h_final = sum_s exp(An * E_s) * dtu_s * B_s,  E_s = sum_{tau>s} dt_tau
__global__ __launch_bounds__(256) void scan_phase1(
    const unsigned* __restrict__ dtu_p, const unsigned* __restrict__ bbp,
    const float* __restrict__ alog, float* __restrict__ hf, float* __restrict__ ap)
{
  __shared__ float lds[4][TC][2];
  int tid = threadIdx.x, w = tid >> 6, l = tid & 63;
  int wid = blockIdx.x * 4 + w;
  int d = wid & (DIN - 1);
  int c = (wid >> 10) & (NCH - 1);
  int b = wid >> 14;
  float An2 = -__expf(alog[d * NS + l]) * 1.44269504f;

  size_t pbase = ((size_t)(b * DIN + d)) * LL + c * TC;
  unsigned p0 = dtu_p[pbase + l];
  unsigned p1 = dtu_p[pbase + 64 + l];
  float s0 = bflo(p0), s1 = bflo(p1);
  // wave64 inclusive prefix scans (DPP)
  s0 = DPP_ADD(s0, 0x111, 0xf); s0 = DPP_ADD(s0, 0x112, 0xf);
  s0 = DPP_ADD(s0, 0x114, 0xf); s0 = DPP_ADD(s0, 0x118, 0xf);
  s0 = DPP_ADD(s0, 0x142, 0xa); s0 = DPP_ADD(s0, 0x143, 0xc);
  s1 = DPP_ADD(s1, 0x111, 0xf); s1 = DPP_ADD(s1, 0x112, 0xf);
  s1 = DPP_ADD(s1, 0x114, 0xf); s1 = DPP_ADD(s1, 0x118, 0xf);
  s1 = DPP_ADD(s1, 0x142, 0xa); s1 = DPP_ADD(s1, 0x143, 0xc);
  float T0 = __uint_as_float(__builtin_amdgcn_readlane(__float_as_uint(s0), 63));
  float T  = T0 + __uint_as_float(__builtin_amdgcn_readlane(__float_as_uint(s1), 63));
  lds[w][l][0]      = T - s0;          // E_t for t = l
  lds[w][l][1]      = bfhi(p0);        // dtu_t
  lds[w][64 + l][0] = (T - T0) - s1;   // E_t for t = 64+l
  lds[w][64 + l][1] = bfhi(p1);
  __syncthreads();

  const unsigned* bq = bbp + ((size_t)(b * 1024 + c * 64) * 64 + l);
  float h0 = 0.f, h1 = 0.f;
  for (int g = 0; g < 16; g++) {
    unsigned bv[4];
    #pragma unroll
    for (int k = 0; k < 4; k++) bv[k] = bq[k * 64];
    const float* gb = &lds[w][g * 8][0];
    #pragma unroll
    for (int j = 0; j < 8; j++) {
      float2 dd = *(const float2*)(gb + j * 2);
      float Bv = (j & 1) ? bfhi(bv[j >> 1]) : bflo(bv[j >> 1]);
      float a = fexp2(dd.x * An2);
      if (j & 1) h1 += a * (dd.y * Bv);
      else       h0 += a * (dd.y * Bv);
    }
    bq += 256;
  }
  size_t o = (((size_t)((b << 10) + d) * NCH) + c) * 64 + l;
  hf[o] = h0 + h1;
  ap[o] = fexp2(T * An2);
}

// ---------------------------------------------------------------- chunked scan, phase 2 (carry combine)
__global__ __launch_bounds__(256) void scan_carry(
    const float* __restrict__ hf, const float* __restrict__ ap,
    float* __restrict__ carry)
{
  int i = blockIdx.x * 256 + threadIdx.x;   // (b, d, n)
  int n = i & 63;
  int d = (i >> 6) & (DIN - 1);
  int b = i >> 16;
  size_t base = ((size_t)((b << 10) + d) * NCH) * 64 + n;
  float cur = 0.f;
  #pragma unroll
  for (int c = 0; c < NCH; c++) {
    carry[base + (size_t)c * 64] = cur;
    cur = ap[base + (size_t)c * 64] * cur + hf[base + (size_t)c * 64];
  }
}

// ---------------------------------------------------------------- chunked scan, phase 3
// recurrence + batched-8 deferred reduce; y staged in LDS, coalesced
// transposed output ymt[b][d][t] (one dword store per lane per chunk).
__global__ __launch_bounds__(256) void scan_phase3(
    const unsigned* __restrict__ dtu_p, const unsigned* __restrict__ sg_p,
    const float2* __restrict__ bcp2, const float* __restrict__ alog,
    const float* __restrict__ carry, ushort* __restrict__ ymt)
{
  __shared__ float lds[4][TC][4];
  __shared__ ushort yt[4][TC];
  int tid = threadIdx.x, w = tid >> 6, l = tid & 63;
  int wid = blockIdx.x * 4 + w;
  int d = wid & (DIN - 1);
  int c = (wid >> 10) & (NCH - 1);
  int b = wid >> 14;
  float An2 = -__expf(alog[d * NS + l]) * 1.44269504f;

  size_t pbase = ((size_t)(b * DIN + d)) * LL + c * TC;
  #pragma unroll
  for (int q = 0; q < 2; q++) {
    unsigned pd = dtu_p[pbase + q * 64 + l];
    unsigned pg = sg_p [pbase + q * 64 + l];
    lds[w][q * 64 + l][0] = bflo(pd);
    lds[w][q * 64 + l][1] = bfhi(pd);
    lds[w][q * 64 + l][2] = bflo(pg);
    lds[w][q * 64 + l][3] = bfhi(pg);
  }
  __syncthreads();

  float h = carry[(((size_t)((b << 10) + d) * NCH) + c) * 64 + l];
  const float2* bq = bcp2 + ((size_t)(b * LL + c * TC)) * 64 + l;
  bool s1f = l & 1, s2f = l & 2, s4f = l & 4;
  bool wl = l < 8;

  for (int g = 0; g < 16; g++) {
    float2 bcv[8];
    #pragma unroll
    for (int k = 0; k < 8; k++) bcv[k] = bq[k * 64];
    const float* gb = &lds[w][g * 8][0];
    float p[8];
    #pragma unroll
    for (int j = 0; j < 8; j++) {
      float2 dd = *(const float2*)(gb + j * 4);
      float a = fexp2(dd.x * An2);
      h = a * h + dd.y * bcv[j].x;
      p[j] = h * bcv[j].y;
    }
    // batched 8-sum reduce over 64 lanes: lane l ends with S_{l&7}
    #pragma unroll
    for (int j = 0; j < 8; j++) p[j] += QP(p[j], 0xB1);       // xor1
    float q0 = s1f ? p[1] : p[0];
    float q1 = s1f ? p[3] : p[2];
    float q2 = s1f ? p[5] : p[4];
    float q3 = s1f ? p[7] : p[6];
    q0 += QP(q0, 0x4E); q1 += QP(q1, 0x4E);                   // xor2
    q2 += QP(q2, 0x4E); q3 += QP(q3, 0x4E);
    float r0 = s2f ? q1 : q0;
    float r1 = s2f ? q3 : q2;
    r0 += SWZ(r0, 0x101F); r1 += SWZ(r1, 0x101F);             // xor4
    float s = s4f ? r1 : r0;
    s += QP(s, 0x128);                                        // xor8 (row_ror:8)
    s += SWZ(s, 0x401F);                                      // xor16
    s += __shfl_xor(s, 32);                                   // xor32

    float2 sgv = *(const float2*)(&lds[w][g * 8 + (l & 7)][2]);
    if (wl) yt[w][g * 8 + l] = f2b(s * sgv.x + sgv.y);
    bq += 512;
  }
  __syncthreads();
  // coalesced transposed write: 128 contiguous bf16 per (b,d,chunk)
  unsigned vv = *(const unsigned*)&yt[w][2 * l];
  ((unsigned*)(ymt + pbase))[l] = vv;
}

// ---------------------------------------------------------------- transpose ymt[b][d][t] -> ym[b][t][d]
__global__ __launch_bounds__(256) void transpose_ym(
    const ushort* __restrict__ ymt, ushort* __restrict__ ym)
{
  __shared__ ushort tile[64][72];
  int tid = threadIdx.x;
  int bx = blockIdx.x;          // d-tile (DIN/64 = 16)
  int by = blockIdx.y;          // t-tile (LL/64 = 32)
  int b  = blockIdx.z;
  int r = tid >> 2, c16 = (tid & 3) * 16;
  const ushort* src = ymt + ((size_t)(b * DIN + bx * 64 + r)) * LL + by * 64 + c16;
  *(uint4*)&tile[r][c16]     = *(const uint4*)src;
  *(uint4*)&tile[r][c16 + 8] = *(const uint4*)(src + 8);
  __syncthreads();
  ushort tmp[16];
  #pragma unroll
  for (int j = 0; j < 16; j++) tmp[j] = tile[c16 + j][r];
  ushort* dst = ym + ((size_t)(b * LL + by * 64 + r)) * DIN + bx * 64 + c16;
  *(uint4*)dst       = *(uint4*)&tmp[0];
  *(uint4*)(dst + 8) = *(uint4*)&tmp[8];
}

// ---------------------------------------------------------------- residual + LayerNorm
__global__ __launch_bounds__(256) void residual_ln(
    const float* __restrict__ x, const float* __restrict__ at,
    const float* __restrict__ mb, const float* __restrict__ lw,
    const float* __restrict__ lb, float* __restrict__ out)
{
  int row = blockIdx.x * 4 + (threadIdx.x >> 6);
  int l = threadIdx.x & 63;
  size_t base = (size_t)row * DD;
  float h[8];
  float s = 0.f, s2 = 0.f;
  #pragma unroll
  for (int half = 0; half < 2; half++) {
    int c = half * 256 + l * 4;
    float4 xv = *(const float4*)(x + base + c);
    float4 av = *(const float4*)(at + base + c);
    float4 mv = *(const float4*)(mb + base + c);
    float* hp = h + half * 4;
    hp[0] = xv.x + av.x + mv.x;
    hp[1] = xv.y + av.y + mv.y;
    hp[2] = xv.z + av.z + mv.z;
    hp[3] = xv.w + av.w + mv.w;
    #pragma unroll
    for (int j = 0; j < 4; j++) { s += hp[j]; s2 += hp[j] * hp[j]; }
  }
  #pragma unroll
  for (int o = 1; o < 64; o <<= 1) { s += __shfl_xor(s, o); s2 += __shfl_xor(s2, o); }
  float mean = s * (1.f / DD);
  float var = s2 * (1.f / DD) - mean * mean;
  float rs = rsqrtf(var + 1e-5f);
  #pragma unroll
  for (int half = 0; half < 2; half++) {
    int c = half * 256 + l * 4;
    float4 ov;
    ov.x = (h[half*4+0] - mean) * rs * lw[c+0] + lb[c+0];
    ov.y = (h[half*4+1] - mean) * rs * lw[c+1] + lb[c+1];
    ov.z = (h[half*4+2] - mean) * rs * lw[c+2] + lb[c+2];
    ov.w = (h[half*4+3] - mean) * rs * lw[c+3] + lb[c+3];
    *(float4*)(out + base + c) = ov;
  }
}

// ---------------------------------------------------------------- host
extern "C" void kernel_launch(void* const* d_in, const int* in_sizes, int n_in,
                              void* d_out, int out_size, void* d_ws, size_t ws_size,
                              hipStream_t stream) {
  const float* x    = (const float*)d_in[0];
  const float* wq   = (const float*)d_in[1];
  const float* bq   = (const float*)d_in[2];
  const float* wk   = (const float*)d_in[3];
  const float* bk   = (const float*)d_in[4];
  const float* wv   = (const float*)d_in[5];
  const float* bv   = (const float*)d_in[6];
  const float* wo   = (const float*)d_in[7];
  const float* bo   = (const float*)d_in[8];
  const float* inw  = (const float*)d_in[9];
  const float* cw   = (const float*)d_in[10];
  const float* cb   = (const float*)d_in[11];
  const float* xpw  = (const float*)d_in[12];
  const float* dtw  = (const float*)d_in[13];
  const float* dtb  = (const float*)d_in[14];
  const float* alog = (const float*)d_in[15];
  const float* dpar = (const float*)d_in[16];
  const float* opw  = (const float*)d_in[17];
  const float* lnw  = (const float*)d_in[18];
  const float* lnb  = (const float*)d_in[19];

  char* ws = (char*)d_ws;
  size_t off = 0;
  auto alloc = [&](size_t bytes) -> void* {
    void* p = ws + off;
    off += (bytes + 255) & ~(size_t)255;
    return p;
  };

  const size_t BLD = (size_t)BL * DD;
  const size_t BLDIN = (size_t)BL * DIN;

  ushort* xf_b   = (ushort*)alloc(BLD * 2);
  ushort* wq_b   = (ushort*)alloc(DD * DD * 2);
  ushort* wk_b   = (ushort*)alloc(DD * DD * 2);
  ushort* wv_b   = (ushort*)alloc(DD * DD * 2);
  ushort* wo_b   = (ushort*)alloc(DD * DD * 2);
  ushort* inw_b  = (ushort*)alloc(2 * DIN * DD * 2);
  ushort* xpw_b  = (ushort*)alloc(160 * DIN * 2);
  ushort* dtw_b  = (ushort*)alloc(DIN * RR * 2);
  ushort* opw_b  = (ushort*)alloc(DD * DIN * 2);
  ushort* q_b    = (ushort*)alloc(BLD * 2);
  ushort* k_b    = (ushort*)alloc(BLD * 2);
  ushort* v_b    = (ushort*)alloc(BLD * 2);
  ushort* ctx_b  = (ushort*)alloc(BLD * 2);
  float*  attn_o = (float*)alloc(BLD * 4);
  float*  xz     = (float*)alloc(BL * (size_t)(2 * DIN) * 4);
  float*  u_f    = (float*)alloc(BLDIN * 4);
  ushort* u_b    = (ushort*)alloc(BLDIN * 2);
  float*  dbc    = (float*)alloc((size_t)BL * 160 * 4);
  ushort* dtc_b  = (ushort*)alloc((size_t)BL * RR * 2);
  float*  dt_f   = (float*)alloc(BLDIN * 4);
  ushort* ym_b   = (ushort*)alloc(BLDIN * 2);
  ushort* ymt_b  = (ushort*)alloc(BLDIN * 2);
  float*  mamba_o= (float*)alloc(BLD * 4);
  unsigned* bbp  = (unsigned*)alloc((size_t)BB * (LL / 2) * NS * 4);      // 0.5 MB
  float2* bcp2   = (float2*)alloc((size_t)BB * LL * NS * sizeof(float2)); // 2.1 MB
  unsigned* dtu_p = (unsigned*)alloc(BLDIN * 4);   // bf16x2, 16.8 MB
  unsigned* sg_p  = (unsigned*)alloc(BLDIN * 4);   // bf16x2, 16.8 MB

  // scan scratch aliased onto xz (xz dead after pack_dtu; phase1 runs later)
  const size_t SCN = (size_t)BB * DIN * NCH * 64;  // 2.1M elems
  float* hf_s    = (float*)xz;
  float* ap_s    = hf_s + SCN;
  float* carry_s = ap_s + SCN;

  // 1) convert inputs to bf16
  CvtJobs cj;
  cj.src[0] = x;    cj.dst[0] = xf_b;  cj.n[0] = (int)BLD;
  cj.src[1] = wq;   cj.dst[1] = wq_b;  cj.n[1] = DD * DD;
  cj.src[2] = wk;   cj.dst[2] = wk_b;  cj.n[2] = DD * DD;
  cj.src[3] = wv;   cj.dst[3] = wv_b;  cj.n[3] = DD * DD;
  cj.src[4] = wo;   cj.dst[4] = wo_b;  cj.n[4] = DD * DD;
  cj.src[5] = inw;  cj.dst[5] = inw_b; cj.n[5] = 2 * DIN * DD;
  cj.src[6] = xpw;  cj.dst[6] = xpw_b; cj.n[6] = 160 * DIN;
  cj.src[7] = dtw;  cj.dst[7] = dtw_b; cj.n[7] = DIN * RR;
  cj.src[8] = opw;  cj.dst[8] = opw_b; cj.n[8] = DD * DIN;
  cvt_multi<<<dim3(256, 9), 256, 0, stream>>>(cj);

  // 2) q,k,v projections
  gemm_bt<<<dim3(8, 64), 256, 0, stream>>>(xf_b, wq_b, bq, nullptr, q_b, BL, DD, DD, 0);
  gemm_bt<<<dim3(8, 64), 256, 0, stream>>>(xf_b, wk_b, bk, nullptr, k_b, BL, DD, DD, 0);
  gemm_bt<<<dim3(8, 64), 256, 0, stream>>>(xf_b, wv_b, bv, nullptr, v_b, BL, DD, DD, 0);

  // 3) flash attention
  flash_attn<<<dim3(32, HH, BB), 256, 0, stream>>>(q_b, k_b, v_b, ctx_b);

  // 4) output projection
  gemm_bt<<<dim3(8, 64), 256, 0, stream>>>(ctx_b, wo_b, bo, attn_o, nullptr, BL, DD, DD, 0);

  // 5) mamba in_proj
  gemm_bt<<<dim3(32, 64), 256, 0, stream>>>(xf_b, inw_b, nullptr, xz, nullptr, BL, 2 * DIN, DD, 0);

  // 6) depthwise conv + SiLU
  conv_silu<<<dim3(32768), 256, 0, stream>>>(xz, cw, cb, u_f, u_b);

  // 7) x_proj
  gemm_bt<<<dim3(3, 64), 256, 0, stream>>>(u_b, xpw_b, nullptr, dbc, nullptr, BL, 160, DIN, 0);

  // 8) dt slice + dt_proj + softplus
  slice_dt<<<dim3(512), 256, 0, stream>>>(dbc, dtc_b);
  gemm_bt<<<dim3(16, 64), 256, 0, stream>>>(dtc_b, dtw_b, dtb, dt_f, nullptr, BL, DIN, RR, 1);

  // 9) pack (B/C and time-major dt/u/gate), then chunked selective scan
  pack_bc<<<dim3(512), 256, 0, stream>>>(dbc, bbp, bcp2);
  pack_dtu<<<dim3(16, 128), 256, 0, stream>>>(dt_f, u_f, xz, dpar, dtu_p, sg_p);
  scan_phase1<<<dim3(8192), 256, 0, stream>>>(dtu_p, bbp, alog, hf_s, ap_s);
  scan_carry<<<dim3(512), 256, 0, stream>>>(hf_s, ap_s, carry_s);
  scan_phase3<<<dim3(8192), 256, 0, stream>>>(dtu_p, sg_p, bcp2, alog, carry_s, ymt_b);
  transpose_ym<<<dim3(16, 32, BB), 256, 0, stream>>>(ymt_b, ym_b);

  // 10) out_proj
  gemm_bt<<<dim3(8, 64), 256, 0, stream>>>(ym_b, opw_b, nullptr, mamba_o, nullptr, BL, DD, DIN, 0);

  // 11) residual + LayerNorm
  residual_ln<<<dim3(1024), 256, 0, stream>>>(x, attn_o, mamba_o, lnw, lnb, (float*)d_out);
}